// Round 4
// baseline (830.111 us; speedup 1.0000x reference)
//
#include <hip/hip_runtime.h>
#include <hip/hip_bf16.h>

#define H 128
#define NREG 8

typedef short short8 __attribute__((ext_vector_type(8)));
typedef float f32x4 __attribute__((ext_vector_type(4)));

__device__ __forceinline__ float bf2f(unsigned short u) {
    union { unsigned int i; float f; } c; c.i = ((unsigned int)u) << 16; return c.f;
}
__device__ __forceinline__ unsigned short f2bf(float f) {
    return __builtin_bit_cast(unsigned short, __float2bfloat16(f));
}

// ---------------- weight prep: wt[m][o][i] = bf16(W_m[i][o])
__global__ void prep_w_kernel(const float* __restrict__ cw1, const float* __restrict__ cw2,
                              unsigned short* __restrict__ wt, int total) {
    int idx = blockIdx.x * 256 + threadIdx.x;
    if (idx >= total) return;
    int m = idx >> 14;
    int o = (idx >> 7) & 127;
    int i = idx & 127;
    const float* srcp = (m < 3) ? (cw1 + (size_t)m * H * H) : (cw2 + (size_t)(m - 3) * H * H);
    wt[idx] = f2bf(srcp[i * H + o]);
}

// ---------------- input projection -> bf16 h
__global__ void proj_kernel(const float* __restrict__ x, const float* __restrict__ pw,
                            const float* __restrict__ pb, unsigned short* __restrict__ hout, int N) {
    int tid = blockIdx.x * 256 + threadIdx.x;
    if (tid >= N * 16) return;
    int i = tid >> 4, c = (tid & 15) * 8;
    float4 xv = *(const float4*)&x[i * 4];
    float acc[8];
#pragma unroll
    for (int j = 0; j < 8; ++j)
        acc[j] = pb[c + j] + xv.x * pw[0 * H + c + j] + xv.y * pw[1 * H + c + j]
               + xv.z * pw[2 * H + c + j] + xv.w * pw[3 * H + c + j];
    short8 o;
#pragma unroll
    for (int j = 0; j < 8; ++j) o[j] = (short)f2bf(acc[j]);
    *(short8*)&hout[(size_t)i * H + c] = o;
}

// ================= CSR build (by dst), region-filtered for XCD write locality ===========
// grid = nchunk*8; reg = blockIdx&7 (-> XCD via round-robin), chunk = blockIdx>>3.
__global__ void count_kernel(const int* __restrict__ dst, int* __restrict__ cnt,
                             int E, int chunk_sz, int regsz) {
    int reg = blockIdx.x & 7;
    int chunk = blockIdx.x >> 3;
    int lo = reg * regsz, hi = lo + regsz;
    int e0 = chunk * chunk_sz;
    int e1 = min(e0 + chunk_sz, E);
    for (int e = e0 + threadIdx.x; e < e1; e += 256) {
        int d = dst[e];
        if (d >= lo && d < hi) atomicAdd(&cnt[d], 1);
    }
}

__global__ void scan_block_kernel(int* __restrict__ data, int* __restrict__ bsum, int n) {
    __shared__ int s[1024];
    int tid = threadIdx.x;
    int i = blockIdx.x * 1024 + tid;
    int v = (i < n) ? data[i] : 0;
    s[tid] = v;
    __syncthreads();
    for (int off = 1; off < 1024; off <<= 1) {
        int t = (tid >= off) ? s[tid - off] : 0;
        __syncthreads();
        s[tid] += t;
        __syncthreads();
    }
    if (i < n) data[i] = s[tid] - v;
    if (tid == 1023) bsum[blockIdx.x] = s[1023];
}

__global__ void scan_sums_kernel(int* __restrict__ bsum, int nb, int* __restrict__ offs, int N) {
    __shared__ int s[128];
    int tid = threadIdx.x;
    int v = (tid < nb) ? bsum[tid] : 0;
    s[tid] = v;
    __syncthreads();
    for (int off = 1; off < 128; off <<= 1) {
        int t = (tid >= off) ? s[tid - off] : 0;
        __syncthreads();
        s[tid] += t;
        __syncthreads();
    }
    if (tid < nb) bsum[tid] = s[tid] - v;
    if (tid == nb - 1) offs[N] = s[tid];
}

__global__ void scan_add_kernel(int* __restrict__ data, const int* __restrict__ bsum, int n) {
    int i = blockIdx.x * 1024 + threadIdx.x;
    if (i < n) data[i] += bsum[blockIdx.x];
}

// fill: bump offs[d] (becomes END pointer); region-filtered like count.
__global__ void fill_kernel(const int* __restrict__ src, const int* __restrict__ dst,
                            int* __restrict__ offs, int* __restrict__ esrc,
                            int E, int chunk_sz, int regsz) {
    int reg = blockIdx.x & 7;
    int chunk = blockIdx.x >> 3;
    int lo = reg * regsz, hi = lo + regsz;
    int e0 = chunk * chunk_sz;
    int e1 = min(e0 + chunk_sz, E);
    for (int e = e0 + threadIdx.x; e < e1; e += 256) {
        int d = dst[e];
        if (d >= lo && d < hi) {
            int p = atomicAdd(&offs[d], 1);
            esrc[p] = src[e];
        }
    }
}

// ---------------- fused GIN layer-1: C = relu((h[row] + sum_nbrs h) @ W1t^T + b1)
// block = 64 rows, 256 threads = 4 waves; gather in fp32 regs -> swizzled LDS -> MFMA.
__global__ __launch_bounds__(256) void gin1_fused_kernel(
    const unsigned short* __restrict__ h, const int* __restrict__ offs,
    const int* __restrict__ esrc, const unsigned short* __restrict__ Wt,
    const float* __restrict__ bias, unsigned short* __restrict__ C, int N) {
    __shared__ unsigned short As[64 * H];   // 16KB, XOR-swizzled, row stride 256B
    __shared__ unsigned short Ws[H * H];    // 32KB, XOR-swizzled
    int bm = blockIdx.x * 64;
    int tid = threadIdx.x;

    // stage W tile
#pragma unroll
    for (int rep = 0; rep < 8; ++rep) {
        int lin = rep * 256 + tid;
        int o = lin >> 4, cb = lin & 15;
        short8 v = *(const short8*)&Wt[(size_t)o * H + cb * 8];
        int byte = o * 256 + ((cb * 16) ^ ((o & 7) << 4));
        *(short8*)((char*)Ws + byte) = v;
    }

    // gather + self -> As (fp32 acc, single bf16 rounding)
    int c = tid & 15;           // 16B chunk
    int rsub = tid >> 4;        // 0..15
#pragma unroll
    for (int rt = 0; rt < 4; ++rt) {
        int r = rt * 16 + rsub;
        int row = bm + r;
        float acc[8] = {};
        if (row < N) {
            short8 v = *(const short8*)&h[(size_t)row * H + c * 8];
#pragma unroll
            for (int j = 0; j < 8; ++j) acc[j] = bf2f((unsigned short)v[j]);
            int s = (row == 0) ? 0 : offs[row - 1];
            int e = offs[row];
            for (int i = s; i < e; ++i) {
                short8 nv = *(const short8*)&h[(size_t)esrc[i] * H + c * 8];
#pragma unroll
                for (int j = 0; j < 8; ++j) acc[j] += bf2f((unsigned short)nv[j]);
            }
        }
        short8 o;
#pragma unroll
        for (int j = 0; j < 8; ++j) o[j] = (short)f2bf(acc[j]);
        int byte = r * 256 + ((c * 16) ^ ((r & 7) << 4));
        *(short8*)((char*)As + byte) = o;
    }
    __syncthreads();

    int lane = tid & 63;
    int w = tid >> 6;
    int wr = (w >> 1) * 32;
    int wc = (w & 1) * 64;
    int lrow = lane & 15, kg = lane >> 4;

    short8 a[2][4];
#pragma unroll
    for (int rt = 0; rt < 2; ++rt)
#pragma unroll
        for (int ks = 0; ks < 4; ++ks) {
            int r = wr + rt * 16 + lrow;
            int kb = ks * 64 + kg * 16;
            a[rt][ks] = *(short8*)((char*)As + r * 256 + (kb ^ ((r & 7) << 4)));
        }

    f32x4 acc[2][4] = {};
#pragma unroll
    for (int ct = 0; ct < 4; ++ct) {
#pragma unroll
        for (int ks = 0; ks < 4; ++ks) {
            int o = wc + ct * 16 + lrow;
            int kb = ks * 64 + kg * 16;
            short8 b = *(short8*)((char*)Ws + o * 256 + (kb ^ ((o & 7) << 4)));
            acc[0][ct] = __builtin_amdgcn_mfma_f32_16x16x32_bf16(a[0][ks], b, acc[0][ct], 0, 0, 0);
            acc[1][ct] = __builtin_amdgcn_mfma_f32_16x16x32_bf16(a[1][ks], b, acc[1][ct], 0, 0, 0);
        }
    }

#pragma unroll
    for (int rt = 0; rt < 2; ++rt)
#pragma unroll
        for (int ct = 0; ct < 4; ++ct)
#pragma unroll
            for (int r = 0; r < 4; ++r) {
                int row = bm + wr + rt * 16 + kg * 4 + r;
                int col = wc + ct * 16 + lrow;
                if (row < N) {
                    float v = fmaxf(acc[rt][ct][r] + bias[col], 0.f);
                    C[(size_t)row * H + col] = f2bf(v);
                }
            }
}

// ---------------- plain MFMA GEMM: C = relu(A @ Wt^T + bias)
__global__ __launch_bounds__(256) void gemm_mfma_kernel(
    const unsigned short* __restrict__ A1,
    const unsigned short* __restrict__ Wt, const float* __restrict__ bias,
    unsigned short* __restrict__ C, int N) {
    __shared__ unsigned short As[64 * H];
    __shared__ unsigned short Ws[H * H];
    int bm = blockIdx.x * 64;
    int tid = threadIdx.x;

#pragma unroll
    for (int rep = 0; rep < 4; ++rep) {
        int lin = rep * 256 + tid;
        int r = lin >> 4, cb = lin & 15;
        int row = bm + r;
        short8 v = {};
        if (row < N) v = *(const short8*)&A1[(size_t)row * H + cb * 8];
        int byte = r * 256 + ((cb * 16) ^ ((r & 7) << 4));
        *(short8*)((char*)As + byte) = v;
    }
#pragma unroll
    for (int rep = 0; rep < 8; ++rep) {
        int lin = rep * 256 + tid;
        int o = lin >> 4, cb = lin & 15;
        short8 v = *(const short8*)&Wt[(size_t)o * H + cb * 8];
        int byte = o * 256 + ((cb * 16) ^ ((o & 7) << 4));
        *(short8*)((char*)Ws + byte) = v;
    }
    __syncthreads();

    int lane = tid & 63;
    int w = tid >> 6;
    int wr = (w >> 1) * 32;
    int wc = (w & 1) * 64;
    int lrow = lane & 15, kg = lane >> 4;

    short8 a[2][4];
#pragma unroll
    for (int rt = 0; rt < 2; ++rt)
#pragma unroll
        for (int ks = 0; ks < 4; ++ks) {
            int r = wr + rt * 16 + lrow;
            int kb = ks * 64 + kg * 16;
            a[rt][ks] = *(short8*)((char*)As + r * 256 + (kb ^ ((r & 7) << 4)));
        }

    f32x4 acc[2][4] = {};
#pragma unroll
    for (int ct = 0; ct < 4; ++ct) {
#pragma unroll
        for (int ks = 0; ks < 4; ++ks) {
            int o = wc + ct * 16 + lrow;
            int kb = ks * 64 + kg * 16;
            short8 b = *(short8*)((char*)Ws + o * 256 + (kb ^ ((o & 7) << 4)));
            acc[0][ct] = __builtin_amdgcn_mfma_f32_16x16x32_bf16(a[0][ks], b, acc[0][ct], 0, 0, 0);
            acc[1][ct] = __builtin_amdgcn_mfma_f32_16x16x32_bf16(a[1][ks], b, acc[1][ct], 0, 0, 0);
        }
    }

#pragma unroll
    for (int rt = 0; rt < 2; ++rt)
#pragma unroll
        for (int ct = 0; ct < 4; ++ct)
#pragma unroll
            for (int r = 0; r < 4; ++r) {
                int row = bm + wr + rt * 16 + kg * 4 + r;
                int col = wc + ct * 16 + lrow;
                if (row < N) {
                    float v = fmaxf(acc[rt][ct][r] + bias[col], 0.f);
                    C[(size_t)row * H + col] = f2bf(v);
                }
            }
}

// ---------------- graph boundaries
__global__ void find_starts_kernel(const int* __restrict__ batch, int* __restrict__ start, int N, int G) {
    int g = blockIdx.x * 256 + threadIdx.x;
    if (g > G) return;
    if (g == G) { start[G] = N; return; }
    int lo = 0, hi = N;
    while (lo < hi) {
        int mid = (lo + hi) >> 1;
        if (batch[mid] < g) lo = mid + 1; else hi = mid;
    }
    start[g] = lo;
}

// ---------------- mean pool + shared head, one block per graph
__global__ __launch_bounds__(128) void pool_head_kernel(
    const unsigned short* __restrict__ h, const int* __restrict__ start,
    const float* __restrict__ sw, const float* __restrict__ sb,
    const float* __restrict__ ew, const float* __restrict__ eb,
    const float* __restrict__ dw, const float* __restrict__ db,
    float* __restrict__ out, int G) {
    int g = blockIdx.x;
    int j = threadIdx.x;
    int s = start[g], e = start[g + 1];
    float sum = 0.f;
    for (int n = s; n < e; ++n) sum += bf2f(h[(size_t)n * H + j]);
    float cnt = (float)(e - s);
    __shared__ float gm[H];
    gm[j] = sum / fmaxf(cnt, 1.0f);
    __syncthreads();
    float t = sb[j];
    for (int k = 0; k < H; ++k) t += gm[k] * sw[k * H + j];
    t = fmaxf(t, 0.f);
    __shared__ float red[2][H];
    red[0][j] = t * ew[j];
    red[1][j] = t * dw[j];
    __syncthreads();
    for (int off = 64; off > 0; off >>= 1) {
        if (j < off) {
            red[0][j] += red[0][j + off];
            red[1][j] += red[1][j + off];
        }
        __syncthreads();
    }
    if (j == 0) {
        out[g] = red[0][0] + eb[0];
        out[G + g] = red[1][0] + db[0];
    }
}

extern "C" void kernel_launch(void* const* d_in, const int* in_sizes, int n_in,
                              void* d_out, int out_size, void* d_ws, size_t ws_size,
                              hipStream_t stream) {
    const float* x      = (const float*)d_in[0];
    const int*   ei     = (const int*)d_in[1];
    const int*   batch  = (const int*)d_in[2];
    const float* proj_w = (const float*)d_in[3];
    const float* proj_b = (const float*)d_in[4];
    const float* cw1    = (const float*)d_in[5];
    const float* cb1    = (const float*)d_in[6];
    const float* cw2    = (const float*)d_in[7];
    const float* cb2    = (const float*)d_in[8];
    const float* sw     = (const float*)d_in[9];
    const float* sb     = (const float*)d_in[10];
    const float* ew     = (const float*)d_in[11];
    const float* eb     = (const float*)d_in[12];
    const float* dw     = (const float*)d_in[13];
    const float* db     = (const float*)d_in[14];

    int N = in_sizes[0] / 4;
    int E = in_sizes[1] / 2;
    int G = out_size / 2;

    const int* src = ei;
    const int* dst = ei + E;

    unsigned short* h   = (unsigned short*)d_ws;          // N*H bf16
    unsigned short* buf = h + (size_t)N * H;              // N*H bf16 (hidden)
    unsigned short* wt  = buf + (size_t)N * H;            // 6*H*H bf16
    int* offs  = (int*)(wt + 6 * H * H);                  // N+1
    int* bsum  = offs + (N + 1);                          // 128
    int* start = bsum + 128;                              // G+1
    int* esrc  = start + (G + 1);                         // E

    float* out = (float*)d_out;

    // ---- CSR build (region-filtered for XCD write locality) ----
    int regsz = (N + NREG - 1) / NREG;
    int chunk_sz = 6144;
    int nchunk = (E + chunk_sz - 1) / chunk_sz;
    hipMemsetAsync(offs, 0, (size_t)(N + 1) * sizeof(int), stream);
    count_kernel<<<nchunk * NREG, 256, 0, stream>>>(dst, offs, E, chunk_sz, regsz);
    int nb = (N + 1023) / 1024;
    scan_block_kernel<<<nb, 1024, 0, stream>>>(offs, bsum, N);
    scan_sums_kernel<<<1, 128, 0, stream>>>(bsum, nb, offs, N);
    scan_add_kernel<<<nb, 1024, 0, stream>>>(offs, bsum, N);
    fill_kernel<<<nchunk * NREG, 256, 0, stream>>>(src, dst, offs, esrc, E, chunk_sz, regsz);

    // ---- weights prep + projection ----
    prep_w_kernel<<<(6 * H * H + 255) / 256, 256, 0, stream>>>(cw1, cw2, wt, 6 * H * H);
    proj_kernel<<<(N * 16 + 255) / 256, 256, 0, stream>>>(x, proj_w, proj_b, h, N);

    int gemm_blocks = (N + 63) / 64;

    for (int l = 0; l < 3; ++l) {
        gin1_fused_kernel<<<gemm_blocks, 256, 0, stream>>>(
            h, offs, esrc, wt + (size_t)l * H * H, cb1 + l * H, buf, N);
        gemm_mfma_kernel<<<gemm_blocks, 256, 0, stream>>>(
            buf, wt + (size_t)(3 + l) * H * H, cb2 + l * H, h, N);
    }

    find_starts_kernel<<<(G + 1 + 255) / 256, 256, 0, stream>>>(batch, start, N, G);
    pool_head_kernel<<<G, 128, 0, stream>>>(h, start, sw, sb, ew, eb, dw, db, out, G);
}

// Round 5
// 570.456 us; speedup vs baseline: 1.4552x; 1.4552x over previous
//
#include <hip/hip_runtime.h>
#include <hip/hip_bf16.h>

#define H 128
#define NREG 8

typedef short short8 __attribute__((ext_vector_type(8)));
typedef float f32x4 __attribute__((ext_vector_type(4)));

__device__ __forceinline__ float bf2f(unsigned short u) {
    union { unsigned int i; float f; } c; c.i = ((unsigned int)u) << 16; return c.f;
}
__device__ __forceinline__ unsigned short f2bf(float f) {
    return __builtin_bit_cast(unsigned short, __float2bfloat16(f));
}

// ---------------- weight prep: wt[m][o][i] = bf16(W_m[i][o])
__global__ void prep_w_kernel(const float* __restrict__ cw1, const float* __restrict__ cw2,
                              unsigned short* __restrict__ wt, int total) {
    int idx = blockIdx.x * 256 + threadIdx.x;
    if (idx >= total) return;
    int m = idx >> 14;
    int o = (idx >> 7) & 127;
    int i = idx & 127;
    const float* srcp = (m < 3) ? (cw1 + (size_t)m * H * H) : (cw2 + (size_t)(m - 3) * H * H);
    wt[idx] = f2bf(srcp[i * H + o]);
}

// ---------------- input projection -> bf16 h
__global__ void proj_kernel(const float* __restrict__ x, const float* __restrict__ pw,
                            const float* __restrict__ pb, unsigned short* __restrict__ hout, int N) {
    int tid = blockIdx.x * 256 + threadIdx.x;
    if (tid >= N * 16) return;
    int i = tid >> 4, c = (tid & 15) * 8;
    float4 xv = *(const float4*)&x[i * 4];
    float acc[8];
#pragma unroll
    for (int j = 0; j < 8; ++j)
        acc[j] = pb[c + j] + xv.x * pw[0 * H + c + j] + xv.y * pw[1 * H + c + j]
               + xv.z * pw[2 * H + c + j] + xv.w * pw[3 * H + c + j];
    short8 o;
#pragma unroll
    for (int j = 0; j < 8; ++j) o[j] = (short)f2bf(acc[j]);
    *(short8*)&hout[(size_t)i * H + c] = o;
}

// ================= CSR build (by dst), region-filtered for XCD write locality ===========
__global__ void count_kernel(const int* __restrict__ dst, int* __restrict__ cnt,
                             int E, int chunk_sz, int regsz) {
    int reg = blockIdx.x & 7;
    int chunk = blockIdx.x >> 3;
    int lo = reg * regsz, hi = lo + regsz;
    int e0 = chunk * chunk_sz;
    int e1 = min(e0 + chunk_sz, E);
    for (int e = e0 + threadIdx.x; e < e1; e += 256) {
        int d = dst[e];
        if (d >= lo && d < hi) atomicAdd(&cnt[d], 1);
    }
}

__global__ void scan_block_kernel(int* __restrict__ data, int* __restrict__ bsum, int n) {
    __shared__ int s[1024];
    int tid = threadIdx.x;
    int i = blockIdx.x * 1024 + tid;
    int v = (i < n) ? data[i] : 0;
    s[tid] = v;
    __syncthreads();
    for (int off = 1; off < 1024; off <<= 1) {
        int t = (tid >= off) ? s[tid - off] : 0;
        __syncthreads();
        s[tid] += t;
        __syncthreads();
    }
    if (i < n) data[i] = s[tid] - v;
    if (tid == 1023) bsum[blockIdx.x] = s[1023];
}

__global__ void scan_sums_kernel(int* __restrict__ bsum, int nb, int* __restrict__ offs, int N) {
    __shared__ int s[128];
    int tid = threadIdx.x;
    int v = (tid < nb) ? bsum[tid] : 0;
    s[tid] = v;
    __syncthreads();
    for (int off = 1; off < 128; off <<= 1) {
        int t = (tid >= off) ? s[tid - off] : 0;
        __syncthreads();
        s[tid] += t;
        __syncthreads();
    }
    if (tid < nb) bsum[tid] = s[tid] - v;
    if (tid == nb - 1) offs[N] = s[tid];
}

__global__ void scan_add_kernel(int* __restrict__ data, const int* __restrict__ bsum, int n) {
    int i = blockIdx.x * 1024 + threadIdx.x;
    if (i < n) data[i] += bsum[blockIdx.x];
}

__global__ void fill_kernel(const int* __restrict__ src, const int* __restrict__ dst,
                            int* __restrict__ offs, int* __restrict__ esrc,
                            int E, int chunk_sz, int regsz) {
    int reg = blockIdx.x & 7;
    int chunk = blockIdx.x >> 3;
    int lo = reg * regsz, hi = lo + regsz;
    int e0 = chunk * chunk_sz;
    int e1 = min(e0 + chunk_sz, E);
    for (int e = e0 + threadIdx.x; e < e1; e += 256) {
        int d = dst[e];
        if (d >= lo && d < hi) {
            int p = atomicAdd(&offs[d], 1);
            esrc[p] = src[e];
        }
    }
}

// ---------------- gather aggregation (bf16 in, fp32 acc, bf16 out), 2-way ILP
__global__ void gather_agg_kernel(const int* __restrict__ offs, const int* __restrict__ esrc,
                                  const unsigned short* __restrict__ h, unsigned short* __restrict__ agg, int N) {
    int tid = blockIdx.x * 256 + threadIdx.x;
    if (tid >= N * 16) return;
    int node = tid >> 4, c = (tid & 15) * 8;
    int s = (node == 0) ? 0 : offs[node - 1];
    int e = offs[node];
    float acc[8] = {};
    int i = s;
    for (; i + 1 < e; i += 2) {
        int s0 = esrc[i], s1 = esrc[i + 1];
        short8 v0 = *(const short8*)&h[(size_t)s0 * H + c];
        short8 v1 = *(const short8*)&h[(size_t)s1 * H + c];
#pragma unroll
        for (int j = 0; j < 8; ++j) acc[j] += bf2f((unsigned short)v0[j]) + bf2f((unsigned short)v1[j]);
    }
    if (i < e) {
        short8 v0 = *(const short8*)&h[(size_t)esrc[i] * H + c];
#pragma unroll
        for (int j = 0; j < 8; ++j) acc[j] += bf2f((unsigned short)v0[j]);
    }
    short8 o;
#pragma unroll
    for (int j = 0; j < 8; ++j) o[j] = (short)f2bf(acc[j]);
    *(short8*)&agg[(size_t)node * H + c] = o;
}

// ---------------- MFMA GEMM: C = relu((A1 (+A2)) @ Wt^T + bias)
template <bool HAS_A2>
__global__ __launch_bounds__(256) void gemm_mfma_kernel(
    const unsigned short* __restrict__ A1, const unsigned short* __restrict__ A2,
    const unsigned short* __restrict__ Wt, const float* __restrict__ bias,
    unsigned short* __restrict__ C, int N) {
    __shared__ unsigned short As[64 * H];
    __shared__ unsigned short Ws[H * H];
    int bm = blockIdx.x * 64;
    int tid = threadIdx.x;

#pragma unroll
    for (int rep = 0; rep < 4; ++rep) {
        int lin = rep * 256 + tid;
        int r = lin >> 4, cb = lin & 15;
        int row = bm + r;
        short8 v = {};
        if (row < N) {
            v = *(const short8*)&A1[(size_t)row * H + cb * 8];
            if (HAS_A2) {
                short8 v2 = *(const short8*)&A2[(size_t)row * H + cb * 8];
#pragma unroll
                for (int j = 0; j < 8; ++j)
                    v[j] = (short)f2bf(bf2f((unsigned short)v[j]) + bf2f((unsigned short)v2[j]));
            }
        }
        int byte = r * 256 + ((cb * 16) ^ ((r & 7) << 4));
        *(short8*)((char*)As + byte) = v;
    }
#pragma unroll
    for (int rep = 0; rep < 8; ++rep) {
        int lin = rep * 256 + tid;
        int o = lin >> 4, cb = lin & 15;
        short8 v = *(const short8*)&Wt[(size_t)o * H + cb * 8];
        int byte = o * 256 + ((cb * 16) ^ ((o & 7) << 4));
        *(short8*)((char*)Ws + byte) = v;
    }
    __syncthreads();

    int lane = tid & 63;
    int w = tid >> 6;
    int wr = (w >> 1) * 32;
    int wc = (w & 1) * 64;
    int lrow = lane & 15, kg = lane >> 4;

    short8 a[2][4];
#pragma unroll
    for (int rt = 0; rt < 2; ++rt)
#pragma unroll
        for (int ks = 0; ks < 4; ++ks) {
            int r = wr + rt * 16 + lrow;
            int kb = ks * 64 + kg * 16;
            a[rt][ks] = *(short8*)((char*)As + r * 256 + (kb ^ ((r & 7) << 4)));
        }

    f32x4 acc[2][4] = {};
#pragma unroll
    for (int ct = 0; ct < 4; ++ct) {
#pragma unroll
        for (int ks = 0; ks < 4; ++ks) {
            int o = wc + ct * 16 + lrow;
            int kb = ks * 64 + kg * 16;
            short8 b = *(short8*)((char*)Ws + o * 256 + (kb ^ ((o & 7) << 4)));
            acc[0][ct] = __builtin_amdgcn_mfma_f32_16x16x32_bf16(a[0][ks], b, acc[0][ct], 0, 0, 0);
            acc[1][ct] = __builtin_amdgcn_mfma_f32_16x16x32_bf16(a[1][ks], b, acc[1][ct], 0, 0, 0);
        }
    }

#pragma unroll
    for (int rt = 0; rt < 2; ++rt)
#pragma unroll
        for (int ct = 0; ct < 4; ++ct)
#pragma unroll
            for (int r = 0; r < 4; ++r) {
                int row = bm + wr + rt * 16 + kg * 4 + r;
                int col = wc + ct * 16 + lrow;
                if (row < N) {
                    float v = fmaxf(acc[rt][ct][r] + bias[col], 0.f);
                    C[(size_t)row * H + col] = f2bf(v);
                }
            }
}

// ---------------- graph boundaries
__global__ void find_starts_kernel(const int* __restrict__ batch, int* __restrict__ start, int N, int G) {
    int g = blockIdx.x * 256 + threadIdx.x;
    if (g > G) return;
    if (g == G) { start[G] = N; return; }
    int lo = 0, hi = N;
    while (lo < hi) {
        int mid = (lo + hi) >> 1;
        if (batch[mid] < g) lo = mid + 1; else hi = mid;
    }
    start[g] = lo;
}

// ---------------- mean pool + shared head, one block per graph
__global__ __launch_bounds__(128) void pool_head_kernel(
    const unsigned short* __restrict__ h, const int* __restrict__ start,
    const float* __restrict__ sw, const float* __restrict__ sb,
    const float* __restrict__ ew, const float* __restrict__ eb,
    const float* __restrict__ dw, const float* __restrict__ db,
    float* __restrict__ out, int G) {
    int g = blockIdx.x;
    int j = threadIdx.x;
    int s = start[g], e = start[g + 1];
    float sum = 0.f;
    for (int n = s; n < e; ++n) sum += bf2f(h[(size_t)n * H + j]);
    float cnt = (float)(e - s);
    __shared__ float gm[H];
    gm[j] = sum / fmaxf(cnt, 1.0f);
    __syncthreads();
    float t = sb[j];
    for (int k = 0; k < H; ++k) t += gm[k] * sw[k * H + j];
    t = fmaxf(t, 0.f);
    __shared__ float red[2][H];
    red[0][j] = t * ew[j];
    red[1][j] = t * dw[j];
    __syncthreads();
    for (int off = 64; off > 0; off >>= 1) {
        if (j < off) {
            red[0][j] += red[0][j + off];
            red[1][j] += red[1][j + off];
        }
        __syncthreads();
    }
    if (j == 0) {
        out[g] = red[0][0] + eb[0];
        out[G + g] = red[1][0] + db[0];
    }
}

extern "C" void kernel_launch(void* const* d_in, const int* in_sizes, int n_in,
                              void* d_out, int out_size, void* d_ws, size_t ws_size,
                              hipStream_t stream) {
    const float* x      = (const float*)d_in[0];
    const int*   ei     = (const int*)d_in[1];
    const int*   batch  = (const int*)d_in[2];
    const float* proj_w = (const float*)d_in[3];
    const float* proj_b = (const float*)d_in[4];
    const float* cw1    = (const float*)d_in[5];
    const float* cb1    = (const float*)d_in[6];
    const float* cw2    = (const float*)d_in[7];
    const float* cb2    = (const float*)d_in[8];
    const float* sw     = (const float*)d_in[9];
    const float* sb     = (const float*)d_in[10];
    const float* ew     = (const float*)d_in[11];
    const float* eb     = (const float*)d_in[12];
    const float* dw     = (const float*)d_in[13];
    const float* db     = (const float*)d_in[14];

    int N = in_sizes[0] / 4;
    int E = in_sizes[1] / 2;
    int G = out_size / 2;

    const int* src = ei;
    const int* dst = ei + E;

    unsigned short* h   = (unsigned short*)d_ws;          // N*H bf16
    unsigned short* buf = h + (size_t)N * H;              // N*H bf16 (agg / hidden)
    unsigned short* wt  = buf + (size_t)N * H;            // 6*H*H bf16
    int* offs  = (int*)(wt + 6 * H * H);                  // N+1
    int* bsum  = offs + (N + 1);                          // 128
    int* start = bsum + 128;                              // G+1
    int* esrc  = start + (G + 1);                         // E

    float* out = (float*)d_out;

    // ---- CSR build (region-filtered) ----
    int regsz = (N + NREG - 1) / NREG;
    int chunk_sz = 6144;
    int nchunk = (E + chunk_sz - 1) / chunk_sz;
    hipMemsetAsync(offs, 0, (size_t)(N + 1) * sizeof(int), stream);
    count_kernel<<<nchunk * NREG, 256, 0, stream>>>(dst, offs, E, chunk_sz, regsz);
    int nb = (N + 1023) / 1024;
    scan_block_kernel<<<nb, 1024, 0, stream>>>(offs, bsum, N);
    scan_sums_kernel<<<1, 128, 0, stream>>>(bsum, nb, offs, N);
    scan_add_kernel<<<nb, 1024, 0, stream>>>(offs, bsum, N);
    fill_kernel<<<nchunk * NREG, 256, 0, stream>>>(src, dst, offs, esrc, E, chunk_sz, regsz);

    // ---- weights prep + projection ----
    prep_w_kernel<<<(6 * H * H + 255) / 256, 256, 0, stream>>>(cw1, cw2, wt, 6 * H * H);
    proj_kernel<<<(N * 16 + 255) / 256, 256, 0, stream>>>(x, proj_w, proj_b, h, N);

    int gemm_blocks = (N + 63) / 64;
    int gather_blocks = (N * 16 + 255) / 256;

    for (int l = 0; l < 3; ++l) {
        gather_agg_kernel<<<gather_blocks, 256, 0, stream>>>(offs, esrc, h, buf, N);
        gemm_mfma_kernel<true><<<gemm_blocks, 256, 0, stream>>>(
            h, buf, wt + (size_t)l * H * H, cb1 + l * H, buf, N);
        gemm_mfma_kernel<false><<<gemm_blocks, 256, 0, stream>>>(
            buf, nullptr, wt + (size_t)(3 + l) * H * H, cb2 + l * H, h, N);
    }

    find_starts_kernel<<<(G + 1 + 255) / 256, 256, 0, stream>>>(batch, start, N, G);
    pool_head_kernel<<<G, 128, 0, stream>>>(h, start, sw, sb, ew, eb, dw, db, out, G);
}

// Round 6
// 544.903 us; speedup vs baseline: 1.5234x; 1.0469x over previous
//
#include <hip/hip_runtime.h>
#include <hip/hip_bf16.h>

#define H 128
#define NREG 8

typedef short short8 __attribute__((ext_vector_type(8)));
typedef float f32x4 __attribute__((ext_vector_type(4)));

__device__ __forceinline__ float bf2f(unsigned short u) {
    union { unsigned int i; float f; } c; c.i = ((unsigned int)u) << 16; return c.f;
}
__device__ __forceinline__ unsigned short f2bf(float f) {
    return __builtin_bit_cast(unsigned short, __float2bfloat16(f));
}

// ---------------- weight prep: wt[m][o][i] = bf16(W_m[i][o])
__global__ void prep_w_kernel(const float* __restrict__ cw1, const float* __restrict__ cw2,
                              unsigned short* __restrict__ wt, int total) {
    int idx = blockIdx.x * 256 + threadIdx.x;
    if (idx >= total) return;
    int m = idx >> 14;
    int o = (idx >> 7) & 127;
    int i = idx & 127;
    const float* srcp = (m < 3) ? (cw1 + (size_t)m * H * H) : (cw2 + (size_t)(m - 3) * H * H);
    wt[idx] = f2bf(srcp[i * H + o]);
}

// ---------------- input projection -> bf16 h
__global__ void proj_kernel(const float* __restrict__ x, const float* __restrict__ pw,
                            const float* __restrict__ pb, unsigned short* __restrict__ hout, int N) {
    int tid = blockIdx.x * 256 + threadIdx.x;
    if (tid >= N * 16) return;
    int i = tid >> 4, c = (tid & 15) * 8;
    float4 xv = *(const float4*)&x[i * 4];
    float acc[8];
#pragma unroll
    for (int j = 0; j < 8; ++j)
        acc[j] = pb[c + j] + xv.x * pw[0 * H + c + j] + xv.y * pw[1 * H + c + j]
               + xv.z * pw[2 * H + c + j] + xv.w * pw[3 * H + c + j];
    short8 o;
#pragma unroll
    for (int j = 0; j < 8; ++j) o[j] = (short)f2bf(acc[j]);
    *(short8*)&hout[(size_t)i * H + c] = o;
}

// ================= CSR build (by dst), region-filtered, nt edge reads ===========
__global__ void count_kernel(const int* __restrict__ dst, int* __restrict__ cnt,
                             int E, int chunk_sz, int regsz) {
    int reg = blockIdx.x & 7;
    int chunk = blockIdx.x >> 3;
    int lo = reg * regsz, hi = lo + regsz;
    int e0 = chunk * chunk_sz;
    int e1 = min(e0 + chunk_sz, E);
    for (int e = e0 + threadIdx.x; e < e1; e += 256) {
        int d = __builtin_nontemporal_load(&dst[e]);
        if (d >= lo && d < hi) atomicAdd(&cnt[d], 1);
    }
}

__global__ void scan_block_kernel(int* __restrict__ data, int* __restrict__ bsum, int n) {
    __shared__ int s[1024];
    int tid = threadIdx.x;
    int i = blockIdx.x * 1024 + tid;
    int v = (i < n) ? data[i] : 0;
    s[tid] = v;
    __syncthreads();
    for (int off = 1; off < 1024; off <<= 1) {
        int t = (tid >= off) ? s[tid - off] : 0;
        __syncthreads();
        s[tid] += t;
        __syncthreads();
    }
    if (i < n) data[i] = s[tid] - v;
    if (tid == 1023) bsum[blockIdx.x] = s[1023];
}

__global__ void scan_sums_kernel(int* __restrict__ bsum, int nb, int* __restrict__ offs, int N) {
    __shared__ int s[128];
    int tid = threadIdx.x;
    int v = (tid < nb) ? bsum[tid] : 0;
    s[tid] = v;
    __syncthreads();
    for (int off = 1; off < 128; off <<= 1) {
        int t = (tid >= off) ? s[tid - off] : 0;
        __syncthreads();
        s[tid] += t;
        __syncthreads();
    }
    if (tid < nb) bsum[tid] = s[tid] - v;
    if (tid == nb - 1) offs[N] = s[tid];
}

__global__ void scan_add_kernel(int* __restrict__ data, const int* __restrict__ bsum, int n) {
    int i = blockIdx.x * 1024 + threadIdx.x;
    if (i < n) data[i] += bsum[blockIdx.x];
}

__global__ void fill_kernel(const int* __restrict__ src, const int* __restrict__ dst,
                            int* __restrict__ offs, int* __restrict__ esrc,
                            int E, int chunk_sz, int regsz) {
    int reg = blockIdx.x & 7;
    int chunk = blockIdx.x >> 3;
    int lo = reg * regsz, hi = lo + regsz;
    int e0 = chunk * chunk_sz;
    int e1 = min(e0 + chunk_sz, E);
    for (int e = e0 + threadIdx.x; e < e1; e += 256) {
        int d = __builtin_nontemporal_load(&dst[e]);
        if (d >= lo && d < hi) {
            int s = __builtin_nontemporal_load(&src[e]);
            int p = atomicAdd(&offs[d], 1);
            esrc[p] = s;
        }
    }
}

// ---------------- gather aggregation (bf16 in, fp32 acc, bf16 out), 2-way ILP
__global__ void gather_agg_kernel(const int* __restrict__ offs, const int* __restrict__ esrc,
                                  const unsigned short* __restrict__ h, unsigned short* __restrict__ agg, int N) {
    int tid = blockIdx.x * 256 + threadIdx.x;
    if (tid >= N * 16) return;
    int node = tid >> 4, c = (tid & 15) * 8;
    int s = (node == 0) ? 0 : offs[node - 1];
    int e = offs[node];
    float acc[8] = {};
    int i = s;
    for (; i + 1 < e; i += 2) {
        int s0 = esrc[i], s1 = esrc[i + 1];
        short8 v0 = *(const short8*)&h[(size_t)s0 * H + c];
        short8 v1 = *(const short8*)&h[(size_t)s1 * H + c];
#pragma unroll
        for (int j = 0; j < 8; ++j) acc[j] += bf2f((unsigned short)v0[j]) + bf2f((unsigned short)v1[j]);
    }
    if (i < e) {
        short8 v0 = *(const short8*)&h[(size_t)esrc[i] * H + c];
#pragma unroll
        for (int j = 0; j < 8; ++j) acc[j] += bf2f((unsigned short)v0[j]);
    }
    short8 o;
#pragma unroll
    for (int j = 0; j < 8; ++j) o[j] = (short)f2bf(acc[j]);
    *(short8*)&agg[(size_t)node * H + c] = o;
}

// ---------------- MFMA GEMM: C = relu((A1 (+A2)) @ Wt^T + bias)
// BM=128 rows, 512 threads = 8 waves (4 row-groups x 2 col-groups), wave = 32 rows x 64 cols.
template <bool HAS_A2>
__global__ __launch_bounds__(512) void gemm_mfma_kernel(
    const unsigned short* __restrict__ A1, const unsigned short* __restrict__ A2,
    const unsigned short* __restrict__ Wt, const float* __restrict__ bias,
    unsigned short* __restrict__ C, int N) {
    __shared__ unsigned short As[128 * H];  // 32KB, XOR-swizzled, row stride 256B
    __shared__ unsigned short Ws[H * H];    // 32KB, XOR-swizzled
    int bm = blockIdx.x * 128;
    int tid = threadIdx.x;

    // stage A tile: 128 rows x 16 chunks / 512 threads = 4 reps
#pragma unroll
    for (int rep = 0; rep < 4; ++rep) {
        int lin = rep * 512 + tid;
        int r = lin >> 4, cb = lin & 15;
        int row = bm + r;
        short8 v = {};
        if (row < N) {
            v = *(const short8*)&A1[(size_t)row * H + cb * 8];
            if (HAS_A2) {
                short8 v2 = *(const short8*)&A2[(size_t)row * H + cb * 8];
#pragma unroll
                for (int j = 0; j < 8; ++j)
                    v[j] = (short)f2bf(bf2f((unsigned short)v[j]) + bf2f((unsigned short)v2[j]));
            }
        }
        int byte = r * 256 + ((cb * 16) ^ ((r & 7) << 4));
        *(short8*)((char*)As + byte) = v;
    }
    // stage W tile: 128 out-cols x 16 chunks / 512 threads = 4 reps
#pragma unroll
    for (int rep = 0; rep < 4; ++rep) {
        int lin = rep * 512 + tid;
        int o = lin >> 4, cb = lin & 15;
        short8 v = *(const short8*)&Wt[(size_t)o * H + cb * 8];
        int byte = o * 256 + ((cb * 16) ^ ((o & 7) << 4));
        *(short8*)((char*)Ws + byte) = v;
    }
    __syncthreads();

    int lane = tid & 63;
    int w = tid >> 6;
    int wr = (w >> 1) * 32;   // 0,32,64,96
    int wc = (w & 1) * 64;    // 0,64
    int lrow = lane & 15, kg = lane >> 4;

    short8 a[2][4];
#pragma unroll
    for (int rt = 0; rt < 2; ++rt)
#pragma unroll
        for (int ks = 0; ks < 4; ++ks) {
            int r = wr + rt * 16 + lrow;
            int kb = ks * 64 + kg * 16;
            a[rt][ks] = *(short8*)((char*)As + r * 256 + (kb ^ ((r & 7) << 4)));
        }

    f32x4 acc[2][4] = {};
#pragma unroll
    for (int ct = 0; ct < 4; ++ct) {
#pragma unroll
        for (int ks = 0; ks < 4; ++ks) {
            int o = wc + ct * 16 + lrow;
            int kb = ks * 64 + kg * 16;
            short8 b = *(short8*)((char*)Ws + o * 256 + (kb ^ ((o & 7) << 4)));
            acc[0][ct] = __builtin_amdgcn_mfma_f32_16x16x32_bf16(a[0][ks], b, acc[0][ct], 0, 0, 0);
            acc[1][ct] = __builtin_amdgcn_mfma_f32_16x16x32_bf16(a[1][ks], b, acc[1][ct], 0, 0, 0);
        }
    }

#pragma unroll
    for (int rt = 0; rt < 2; ++rt)
#pragma unroll
        for (int ct = 0; ct < 4; ++ct)
#pragma unroll
            for (int r = 0; r < 4; ++r) {
                int row = bm + wr + rt * 16 + kg * 4 + r;
                int col = wc + ct * 16 + lrow;
                if (row < N) {
                    float v = fmaxf(acc[rt][ct][r] + bias[col], 0.f);
                    C[(size_t)row * H + col] = f2bf(v);
                }
            }
}

// ---------------- graph boundaries
__global__ void find_starts_kernel(const int* __restrict__ batch, int* __restrict__ start, int N, int G) {
    int g = blockIdx.x * 256 + threadIdx.x;
    if (g > G) return;
    if (g == G) { start[G] = N; return; }
    int lo = 0, hi = N;
    while (lo < hi) {
        int mid = (lo + hi) >> 1;
        if (batch[mid] < g) lo = mid + 1; else hi = mid;
    }
    start[g] = lo;
}

// ---------------- mean pool + shared head, one block per graph
__global__ __launch_bounds__(128) void pool_head_kernel(
    const unsigned short* __restrict__ h, const int* __restrict__ start,
    const float* __restrict__ sw, const float* __restrict__ sb,
    const float* __restrict__ ew, const float* __restrict__ eb,
    const float* __restrict__ dw, const float* __restrict__ db,
    float* __restrict__ out, int G) {
    int g = blockIdx.x;
    int j = threadIdx.x;
    int s = start[g], e = start[g + 1];
    float sum = 0.f;
    for (int n = s; n < e; ++n) sum += bf2f(h[(size_t)n * H + j]);
    float cnt = (float)(e - s);
    __shared__ float gm[H];
    gm[j] = sum / fmaxf(cnt, 1.0f);
    __syncthreads();
    float t = sb[j];
    for (int k = 0; k < H; ++k) t += gm[k] * sw[k * H + j];
    t = fmaxf(t, 0.f);
    __shared__ float red[2][H];
    red[0][j] = t * ew[j];
    red[1][j] = t * dw[j];
    __syncthreads();
    for (int off = 64; off > 0; off >>= 1) {
        if (j < off) {
            red[0][j] += red[0][j + off];
            red[1][j] += red[1][j + off];
        }
        __syncthreads();
    }
    if (j == 0) {
        out[g] = red[0][0] + eb[0];
        out[G + g] = red[1][0] + db[0];
    }
}

extern "C" void kernel_launch(void* const* d_in, const int* in_sizes, int n_in,
                              void* d_out, int out_size, void* d_ws, size_t ws_size,
                              hipStream_t stream) {
    const float* x      = (const float*)d_in[0];
    const int*   ei     = (const int*)d_in[1];
    const int*   batch  = (const int*)d_in[2];
    const float* proj_w = (const float*)d_in[3];
    const float* proj_b = (const float*)d_in[4];
    const float* cw1    = (const float*)d_in[5];
    const float* cb1    = (const float*)d_in[6];
    const float* cw2    = (const float*)d_in[7];
    const float* cb2    = (const float*)d_in[8];
    const float* sw     = (const float*)d_in[9];
    const float* sb     = (const float*)d_in[10];
    const float* ew     = (const float*)d_in[11];
    const float* eb     = (const float*)d_in[12];
    const float* dw     = (const float*)d_in[13];
    const float* db     = (const float*)d_in[14];

    int N = in_sizes[0] / 4;
    int E = in_sizes[1] / 2;
    int G = out_size / 2;

    const int* src = ei;
    const int* dst = ei + E;

    unsigned short* h   = (unsigned short*)d_ws;          // N*H bf16
    unsigned short* buf = h + (size_t)N * H;              // N*H bf16 (agg / hidden)
    unsigned short* wt  = buf + (size_t)N * H;            // 6*H*H bf16
    int* offs  = (int*)(wt + 6 * H * H);                  // N+1
    int* bsum  = offs + (N + 1);                          // 128
    int* start = bsum + 128;                              // G+1
    int* esrc  = start + (G + 1);                         // E

    float* out = (float*)d_out;

    // ---- CSR build (region-filtered, nt reads) ----
    int regsz = (N + NREG - 1) / NREG;
    int chunk_sz = 6144;
    int nchunk = (E + chunk_sz - 1) / chunk_sz;
    hipMemsetAsync(offs, 0, (size_t)(N + 1) * sizeof(int), stream);
    count_kernel<<<nchunk * NREG, 256, 0, stream>>>(dst, offs, E, chunk_sz, regsz);
    int nb = (N + 1023) / 1024;
    scan_block_kernel<<<nb, 1024, 0, stream>>>(offs, bsum, N);
    scan_sums_kernel<<<1, 128, 0, stream>>>(bsum, nb, offs, N);
    scan_add_kernel<<<nb, 1024, 0, stream>>>(offs, bsum, N);
    fill_kernel<<<nchunk * NREG, 256, 0, stream>>>(src, dst, offs, esrc, E, chunk_sz, regsz);

    // ---- weights prep + projection ----
    prep_w_kernel<<<(6 * H * H + 255) / 256, 256, 0, stream>>>(cw1, cw2, wt, 6 * H * H);
    proj_kernel<<<(N * 16 + 255) / 256, 256, 0, stream>>>(x, proj_w, proj_b, h, N);

    int gemm_blocks = (N + 127) / 128;
    int gather_blocks = (N * 16 + 255) / 256;

    for (int l = 0; l < 3; ++l) {
        gather_agg_kernel<<<gather_blocks, 256, 0, stream>>>(offs, esrc, h, buf, N);
        gemm_mfma_kernel<true><<<gemm_blocks, 512, 0, stream>>>(
            h, buf, wt + (size_t)l * H * H, cb1 + l * H, buf, N);
        gemm_mfma_kernel<false><<<gemm_blocks, 512, 0, stream>>>(
            buf, nullptr, wt + (size_t)(3 + l) * H * H, cb2 + l * H, h, N);
    }

    find_starts_kernel<<<(G + 1 + 255) / 256, 256, 0, stream>>>(batch, start, N, G);
    pool_head_kernel<<<G, 128, 0, stream>>>(h, start, sw, sb, ew, eb, dw, db, out, G);
}

// Round 7
// 522.508 us; speedup vs baseline: 1.5887x; 1.0429x over previous
//
#include <hip/hip_runtime.h>
#include <hip/hip_bf16.h>

#define H 128
#define NREG 8

typedef short short8 __attribute__((ext_vector_type(8)));
typedef float f32x4 __attribute__((ext_vector_type(4)));

__device__ __forceinline__ float bf2f(unsigned short u) {
    union { unsigned int i; float f; } c; c.i = ((unsigned int)u) << 16; return c.f;
}
__device__ __forceinline__ unsigned short f2bf(float f) {
    return __builtin_bit_cast(unsigned short, __float2bfloat16(f));
}

// ---------------- weight prep: wt[m][o][i] = bf16(W_m[i][o])
__global__ void prep_w_kernel(const float* __restrict__ cw1, const float* __restrict__ cw2,
                              unsigned short* __restrict__ wt, int total) {
    int idx = blockIdx.x * 256 + threadIdx.x;
    if (idx >= total) return;
    int m = idx >> 14;
    int o = (idx >> 7) & 127;
    int i = idx & 127;
    const float* srcp = (m < 3) ? (cw1 + (size_t)m * H * H) : (cw2 + (size_t)(m - 3) * H * H);
    wt[idx] = f2bf(srcp[i * H + o]);
}

// ---------------- input projection -> bf16 h
__global__ void proj_kernel(const float* __restrict__ x, const float* __restrict__ pw,
                            const float* __restrict__ pb, unsigned short* __restrict__ hout, int N) {
    int tid = blockIdx.x * 256 + threadIdx.x;
    if (tid >= N * 16) return;
    int i = tid >> 4, c = (tid & 15) * 8;
    float4 xv = *(const float4*)&x[i * 4];
    float acc[8];
#pragma unroll
    for (int j = 0; j < 8; ++j)
        acc[j] = pb[c + j] + xv.x * pw[0 * H + c + j] + xv.y * pw[1 * H + c + j]
               + xv.z * pw[2 * H + c + j] + xv.w * pw[3 * H + c + j];
    short8 o;
#pragma unroll
    for (int j = 0; j < 8; ++j) o[j] = (short)f2bf(acc[j]);
    *(short8*)&hout[(size_t)i * H + c] = o;
}

// ================= CSR build: partition into region buckets, then local count/fill =====
// bucket entry: (dstLocal << 17) | src   (dstLocal < 2^14, src < 2^17)
__global__ void partition_kernel(const int* __restrict__ src, const int* __restrict__ dst,
                                 int* __restrict__ rcnt, int* __restrict__ bucket,
                                 int E, int regsz, int cap) {
    __shared__ int hcnt[NREG];
    __shared__ int hbase[NREG];
    int tid = threadIdx.x;
    if (tid < NREG) hcnt[tid] = 0;
    __syncthreads();
    int e0 = blockIdx.x * 1024;
    int regv[4], pk[4];
    bool act[4];
#pragma unroll
    for (int k = 0; k < 4; ++k) {
        int e = e0 + k * 256 + tid;
        act[k] = e < E;
        regv[k] = 0; pk[k] = 0;
        if (act[k]) {
            int d = __builtin_nontemporal_load(&dst[e]);
            int s = __builtin_nontemporal_load(&src[e]);
            int r = d / regsz;
            regv[k] = r;
            pk[k] = ((d - r * regsz) << 17) | s;
            atomicAdd(&hcnt[r], 1);
        }
    }
    __syncthreads();
    if (tid < NREG) {
        hbase[tid] = atomicAdd(&rcnt[tid], hcnt[tid]);
        hcnt[tid] = 0;   // reuse as cursor
    }
    __syncthreads();
#pragma unroll
    for (int k = 0; k < 4; ++k) {
        if (act[k]) {
            int r = regv[k];
            int pos = hbase[r] + atomicAdd(&hcnt[r], 1);
            if (pos < cap) bucket[r * cap + pos] = pk[k];
        }
    }
}

__global__ void count2_kernel(const int* __restrict__ bucket, const int* __restrict__ rcnt,
                              int* __restrict__ cnt, int regsz, int cap, int per_block) {
    int r = blockIdx.x & 7;
    int c = blockIdx.x >> 3;
    int n = min(rcnt[r], cap);
    int lo = r * regsz;
    int p0 = c * per_block;
    int p1 = min(p0 + per_block, n);
    for (int p = p0 + threadIdx.x; p < p1; p += 256) {
        int v = bucket[r * cap + p];
        atomicAdd(&cnt[lo + (v >> 17)], 1);
    }
}

__global__ void scan_block_kernel(int* __restrict__ data, int* __restrict__ bsum, int n) {
    __shared__ int s[1024];
    int tid = threadIdx.x;
    int i = blockIdx.x * 1024 + tid;
    int v = (i < n) ? data[i] : 0;
    s[tid] = v;
    __syncthreads();
    for (int off = 1; off < 1024; off <<= 1) {
        int t = (tid >= off) ? s[tid - off] : 0;
        __syncthreads();
        s[tid] += t;
        __syncthreads();
    }
    if (i < n) data[i] = s[tid] - v;
    if (tid == 1023) bsum[blockIdx.x] = s[1023];
}

__global__ void scan_sums_kernel(int* __restrict__ bsum, int nb, int* __restrict__ offs, int N) {
    __shared__ int s[128];
    int tid = threadIdx.x;
    int v = (tid < nb) ? bsum[tid] : 0;
    s[tid] = v;
    __syncthreads();
    for (int off = 1; off < 128; off <<= 1) {
        int t = (tid >= off) ? s[tid - off] : 0;
        __syncthreads();
        s[tid] += t;
        __syncthreads();
    }
    if (tid < nb) bsum[tid] = s[tid] - v;
    if (tid == nb - 1) offs[N] = s[tid];
}

__global__ void scan_add_kernel(int* __restrict__ data, const int* __restrict__ bsum, int n) {
    int i = blockIdx.x * 1024 + threadIdx.x;
    if (i < n) data[i] += bsum[blockIdx.x];
}

__global__ void fill2_kernel(const int* __restrict__ bucket, const int* __restrict__ rcnt,
                             int* __restrict__ offs, int* __restrict__ esrc,
                             int regsz, int cap, int per_block) {
    int r = blockIdx.x & 7;
    int c = blockIdx.x >> 3;
    int n = min(rcnt[r], cap);
    int lo = r * regsz;
    int p0 = c * per_block;
    int p1 = min(p0 + per_block, n);
    for (int p = p0 + threadIdx.x; p < p1; p += 256) {
        int v = bucket[r * cap + p];
        int pos = atomicAdd(&offs[lo + (v >> 17)], 1);
        esrc[pos] = v & 0x1FFFF;
    }
}

// ---------------- gather aggregation (bf16 in, fp32 acc, bf16 out), 4-way ILP
__global__ void gather_agg_kernel(const int* __restrict__ offs, const int* __restrict__ esrc,
                                  const unsigned short* __restrict__ h, unsigned short* __restrict__ agg, int N) {
    int tid = blockIdx.x * 256 + threadIdx.x;
    if (tid >= N * 16) return;
    int node = tid >> 4, c = (tid & 15) * 8;
    int s = (node == 0) ? 0 : offs[node - 1];
    int e = offs[node];
    float acc[8] = {};
    int i = s;
    for (; i + 3 < e; i += 4) {
        int s0 = esrc[i], s1 = esrc[i + 1], s2 = esrc[i + 2], s3 = esrc[i + 3];
        short8 v0 = *(const short8*)&h[(size_t)s0 * H + c];
        short8 v1 = *(const short8*)&h[(size_t)s1 * H + c];
        short8 v2 = *(const short8*)&h[(size_t)s2 * H + c];
        short8 v3 = *(const short8*)&h[(size_t)s3 * H + c];
#pragma unroll
        for (int j = 0; j < 8; ++j)
            acc[j] += (bf2f((unsigned short)v0[j]) + bf2f((unsigned short)v1[j]))
                    + (bf2f((unsigned short)v2[j]) + bf2f((unsigned short)v3[j]));
    }
    for (; i < e; ++i) {
        short8 v0 = *(const short8*)&h[(size_t)esrc[i] * H + c];
#pragma unroll
        for (int j = 0; j < 8; ++j) acc[j] += bf2f((unsigned short)v0[j]);
    }
    short8 o;
#pragma unroll
    for (int j = 0; j < 8; ++j) o[j] = (short)f2bf(acc[j]);
    *(short8*)&agg[(size_t)node * H + c] = o;
}

// ---------------- MFMA GEMM: C = relu((A1 (+A2)) @ Wt^T + bias)
// BM=128 rows, 512 threads = 8 waves (4 row-groups x 2 col-groups), wave = 32 rows x 64 cols.
template <bool HAS_A2>
__global__ __launch_bounds__(512) void gemm_mfma_kernel(
    const unsigned short* __restrict__ A1, const unsigned short* __restrict__ A2,
    const unsigned short* __restrict__ Wt, const float* __restrict__ bias,
    unsigned short* __restrict__ C, int N) {
    __shared__ unsigned short As[128 * H];
    __shared__ unsigned short Ws[H * H];
    int bm = blockIdx.x * 128;
    int tid = threadIdx.x;

#pragma unroll
    for (int rep = 0; rep < 4; ++rep) {
        int lin = rep * 512 + tid;
        int r = lin >> 4, cb = lin & 15;
        int row = bm + r;
        short8 v = {};
        if (row < N) {
            v = *(const short8*)&A1[(size_t)row * H + cb * 8];
            if (HAS_A2) {
                short8 v2 = *(const short8*)&A2[(size_t)row * H + cb * 8];
#pragma unroll
                for (int j = 0; j < 8; ++j)
                    v[j] = (short)f2bf(bf2f((unsigned short)v[j]) + bf2f((unsigned short)v2[j]));
            }
        }
        int byte = r * 256 + ((cb * 16) ^ ((r & 7) << 4));
        *(short8*)((char*)As + byte) = v;
    }
#pragma unroll
    for (int rep = 0; rep < 4; ++rep) {
        int lin = rep * 512 + tid;
        int o = lin >> 4, cb = lin & 15;
        short8 v = *(const short8*)&Wt[(size_t)o * H + cb * 8];
        int byte = o * 256 + ((cb * 16) ^ ((o & 7) << 4));
        *(short8*)((char*)Ws + byte) = v;
    }
    __syncthreads();

    int lane = tid & 63;
    int w = tid >> 6;
    int wr = (w >> 1) * 32;
    int wc = (w & 1) * 64;
    int lrow = lane & 15, kg = lane >> 4;

    short8 a[2][4];
#pragma unroll
    for (int rt = 0; rt < 2; ++rt)
#pragma unroll
        for (int ks = 0; ks < 4; ++ks) {
            int r = wr + rt * 16 + lrow;
            int kb = ks * 64 + kg * 16;
            a[rt][ks] = *(short8*)((char*)As + r * 256 + (kb ^ ((r & 7) << 4)));
        }

    f32x4 acc[2][4] = {};
#pragma unroll
    for (int ct = 0; ct < 4; ++ct) {
#pragma unroll
        for (int ks = 0; ks < 4; ++ks) {
            int o = wc + ct * 16 + lrow;
            int kb = ks * 64 + kg * 16;
            short8 b = *(short8*)((char*)Ws + o * 256 + (kb ^ ((o & 7) << 4)));
            acc[0][ct] = __builtin_amdgcn_mfma_f32_16x16x32_bf16(a[0][ks], b, acc[0][ct], 0, 0, 0);
            acc[1][ct] = __builtin_amdgcn_mfma_f32_16x16x32_bf16(a[1][ks], b, acc[1][ct], 0, 0, 0);
        }
    }

#pragma unroll
    for (int rt = 0; rt < 2; ++rt)
#pragma unroll
        for (int ct = 0; ct < 4; ++ct)
#pragma unroll
            for (int r = 0; r < 4; ++r) {
                int row = bm + wr + rt * 16 + kg * 4 + r;
                int col = wc + ct * 16 + lrow;
                if (row < N) {
                    float v = fmaxf(acc[rt][ct][r] + bias[col], 0.f);
                    C[(size_t)row * H + col] = f2bf(v);
                }
            }
}

// ---------------- graph boundaries
__global__ void find_starts_kernel(const int* __restrict__ batch, int* __restrict__ start, int N, int G) {
    int g = blockIdx.x * 256 + threadIdx.x;
    if (g > G) return;
    if (g == G) { start[G] = N; return; }
    int lo = 0, hi = N;
    while (lo < hi) {
        int mid = (lo + hi) >> 1;
        if (batch[mid] < g) lo = mid + 1; else hi = mid;
    }
    start[g] = lo;
}

// ---------------- mean pool + shared head, one block per graph
__global__ __launch_bounds__(128) void pool_head_kernel(
    const unsigned short* __restrict__ h, const int* __restrict__ start,
    const float* __restrict__ sw, const float* __restrict__ sb,
    const float* __restrict__ ew, const float* __restrict__ eb,
    const float* __restrict__ dw, const float* __restrict__ db,
    float* __restrict__ out, int G) {
    int g = blockIdx.x;
    int j = threadIdx.x;
    int s = start[g], e = start[g + 1];
    float sum = 0.f;
    for (int n = s; n < e; ++n) sum += bf2f(h[(size_t)n * H + j]);
    float cnt = (float)(e - s);
    __shared__ float gm[H];
    gm[j] = sum / fmaxf(cnt, 1.0f);
    __syncthreads();
    float t = sb[j];
    for (int k = 0; k < H; ++k) t += gm[k] * sw[k * H + j];
    t = fmaxf(t, 0.f);
    __shared__ float red[2][H];
    red[0][j] = t * ew[j];
    red[1][j] = t * dw[j];
    __syncthreads();
    for (int off = 64; off > 0; off >>= 1) {
        if (j < off) {
            red[0][j] += red[0][j + off];
            red[1][j] += red[1][j + off];
        }
        __syncthreads();
    }
    if (j == 0) {
        out[g] = red[0][0] + eb[0];
        out[G + g] = red[1][0] + db[0];
    }
}

extern "C" void kernel_launch(void* const* d_in, const int* in_sizes, int n_in,
                              void* d_out, int out_size, void* d_ws, size_t ws_size,
                              hipStream_t stream) {
    const float* x      = (const float*)d_in[0];
    const int*   ei     = (const int*)d_in[1];
    const int*   batch  = (const int*)d_in[2];
    const float* proj_w = (const float*)d_in[3];
    const float* proj_b = (const float*)d_in[4];
    const float* cw1    = (const float*)d_in[5];
    const float* cb1    = (const float*)d_in[6];
    const float* cw2    = (const float*)d_in[7];
    const float* cb2    = (const float*)d_in[8];
    const float* sw     = (const float*)d_in[9];
    const float* sb     = (const float*)d_in[10];
    const float* ew     = (const float*)d_in[11];
    const float* eb     = (const float*)d_in[12];
    const float* dw     = (const float*)d_in[13];
    const float* db     = (const float*)d_in[14];

    int N = in_sizes[0] / 4;
    int E = in_sizes[1] / 2;
    int G = out_size / 2;

    const int* src = ei;
    const int* dst = ei + E;

    unsigned short* h   = (unsigned short*)d_ws;          // N*H bf16
    unsigned short* buf = h + (size_t)N * H;              // N*H bf16 (agg / hidden; bucket overlaps)
    unsigned short* wt  = buf + (size_t)N * H;            // 6*H*H bf16
    int* offs  = (int*)(wt + 6 * H * H);                  // N+1
    int* bsum  = offs + (N + 1);                          // 128
    int* rcnt  = bsum + 128;                              // 8
    int* start = rcnt + 8;                                // G+1
    int* esrc  = start + (G + 1);                         // E
    int* bucket = (int*)buf;                              // 8*cap ints, overlaps buf (free until layer loop)

    float* out = (float*)d_out;

    int regsz = (N + NREG - 1) / NREG;
    int cap = E / NREG + E / (NREG * 4) + 1024;

    // zero offs + bsum + rcnt in one shot (contiguous)
    hipMemsetAsync(offs, 0, (size_t)(N + 1 + 128 + 8) * sizeof(int), stream);

    // ---- CSR build: partition -> region-local count -> scan -> region-local fill ----
    partition_kernel<<<(E + 1023) / 1024, 256, 0, stream>>>(src, dst, rcnt, bucket, E, regsz, cap);
    int per_block = 2048;
    int nchunk2 = (cap + per_block - 1) / per_block;
    count2_kernel<<<nchunk2 * NREG, 256, 0, stream>>>(bucket, rcnt, offs, regsz, cap, per_block);
    int nb = (N + 1023) / 1024;
    scan_block_kernel<<<nb, 1024, 0, stream>>>(offs, bsum, N);
    scan_sums_kernel<<<1, 128, 0, stream>>>(bsum, nb, offs, N);
    scan_add_kernel<<<nb, 1024, 0, stream>>>(offs, bsum, N);
    fill2_kernel<<<nchunk2 * NREG, 256, 0, stream>>>(bucket, rcnt, offs, esrc, regsz, cap, per_block);

    // ---- weights prep + projection ----
    prep_w_kernel<<<(6 * H * H + 255) / 256, 256, 0, stream>>>(cw1, cw2, wt, 6 * H * H);
    proj_kernel<<<(N * 16 + 255) / 256, 256, 0, stream>>>(x, proj_w, proj_b, h, N);

    int gemm_blocks = (N + 127) / 128;
    int gather_blocks = (N * 16 + 255) / 256;

    for (int l = 0; l < 3; ++l) {
        gather_agg_kernel<<<gather_blocks, 256, 0, stream>>>(offs, esrc, h, buf, N);
        gemm_mfma_kernel<true><<<gemm_blocks, 512, 0, stream>>>(
            h, buf, wt + (size_t)l * H * H, cb1 + l * H, buf, N);
        gemm_mfma_kernel<false><<<gemm_blocks, 512, 0, stream>>>(
            buf, nullptr, wt + (size_t)(3 + l) * H * H, cb2 + l * H, h, N);
    }

    find_starts_kernel<<<(G + 1 + 255) / 256, 256, 0, stream>>>(batch, start, N, G);
    pool_head_kernel<<<G, 128, 0, stream>>>(h, start, sw, sb, ew, eb, dw, db, out, G);
}

// Round 8
// 405.280 us; speedup vs baseline: 2.0482x; 1.2893x over previous
//
#include <hip/hip_runtime.h>
#include <hip/hip_bf16.h>

#define H 128
#define REGSZ 512      // nodes per region (power of 2)
#define PCHUNK 4096    // edges per partition block

typedef short short8 __attribute__((ext_vector_type(8)));
typedef float f32x4 __attribute__((ext_vector_type(4)));

__device__ __forceinline__ float bf2f(unsigned short u) {
    union { unsigned int i; float f; } c; c.i = ((unsigned int)u) << 16; return c.f;
}
__device__ __forceinline__ unsigned short f2bf(float f) {
    return __builtin_bit_cast(unsigned short, __float2bfloat16(f));
}

// ---------------- weight prep: wt[m][o][i] = bf16(W_m[i][o])
__global__ void prep_w_kernel(const float* __restrict__ cw1, const float* __restrict__ cw2,
                              unsigned short* __restrict__ wt, int total) {
    int idx = blockIdx.x * 256 + threadIdx.x;
    if (idx >= total) return;
    int m = idx >> 14;
    int o = (idx >> 7) & 127;
    int i = idx & 127;
    const float* srcp = (m < 3) ? (cw1 + (size_t)m * H * H) : (cw2 + (size_t)(m - 3) * H * H);
    wt[idx] = f2bf(srcp[i * H + o]);
}

// ---------------- input projection -> bf16 h
__global__ void proj_kernel(const float* __restrict__ x, const float* __restrict__ pw,
                            const float* __restrict__ pb, unsigned short* __restrict__ hout, int N) {
    int tid = blockIdx.x * 256 + threadIdx.x;
    if (tid >= N * 16) return;
    int i = tid >> 4, c = (tid & 15) * 8;
    float4 xv = *(const float4*)&x[i * 4];
    float acc[8];
#pragma unroll
    for (int j = 0; j < 8; ++j)
        acc[j] = pb[c + j] + xv.x * pw[0 * H + c + j] + xv.y * pw[1 * H + c + j]
               + xv.z * pw[2 * H + c + j] + xv.w * pw[3 * H + c + j];
    short8 o;
#pragma unroll
    for (int j = 0; j < 8; ++j) o[j] = (short)f2bf(acc[j]);
    *(short8*)&hout[(size_t)i * H + c] = o;
}

// ================= CSR build =================
// bucket entry: (dstLocal << 17) | src   (dstLocal < 512, src < 2^17)
__global__ __launch_bounds__(256) void partition_kernel(
    const int* __restrict__ src, const int* __restrict__ dst,
    int* __restrict__ rcnt, int* __restrict__ bucket,
    int E, int nreg, int cap) {
    __shared__ int hcnt[256];
    __shared__ int hbase[256];
    int tid = threadIdx.x;
    hcnt[tid] = 0;
    __syncthreads();
    int e0 = blockIdx.x * PCHUNK;
    int e1 = min(e0 + PCHUNK, E);
    // pass 1: histogram regions
    for (int e = e0 + tid; e < e1; e += 256)
        atomicAdd(&hcnt[dst[e] >> 9], 1);
    __syncthreads();
    // reserve global slots (one atomic per non-empty region)
    {
        int c = hcnt[tid];
        hbase[tid] = (c > 0) ? atomicAdd(&rcnt[tid], c) : 0;
        hcnt[tid] = 0;  // reuse as cursor
    }
    __syncthreads();
    // pass 2: write packed entries (dense runs per region)
    for (int e = e0 + tid; e < e1; e += 256) {
        int d = dst[e], s = src[e];
        int r = d >> 9;
        int pos = hbase[r] + atomicAdd(&hcnt[r], 1);
        if (pos < cap) bucket[(size_t)r * cap + pos] = ((d & (REGSZ - 1)) << 17) | s;
    }
}

// one block per region: local histogram -> LDS scan -> place -> write offs ends.
// All esrc writes land in the region's contiguous window (block-local L2 absorption).
__global__ __launch_bounds__(256) void csr_region_kernel(
    const int* __restrict__ rcnt, const int* __restrict__ bucket,
    int* __restrict__ offs, int* __restrict__ esrc,
    int N, int nreg, int cap) {
    __shared__ int cnt[REGSZ];
    __shared__ int part[256];
    __shared__ int sbase;
    int r = blockIdx.x;
    int tid = threadIdx.x;

    // base = prefix-sum of rcnt over regions < r (256-wide scan covers nreg<=256)
    int v = (tid < nreg) ? rcnt[tid] : 0;
    part[tid] = v;
    __syncthreads();
    for (int off = 1; off < 256; off <<= 1) {
        int t = (tid >= off) ? part[tid - off] : 0;
        __syncthreads();
        part[tid] += t;
        __syncthreads();
    }
    if (tid == 0) sbase = (r == 0) ? 0 : part[r - 1];
    cnt[tid] = 0;
    cnt[tid + 256] = 0;
    __syncthreads();
    int base = sbase;
    int n = min(part[r] - base, cap);
    const int* bk = bucket + (size_t)r * cap;

    // phase A: histogram dstLocal
    for (int p = tid; p < n; p += 256)
        atomicAdd(&cnt[bk[p] >> 17], 1);
    __syncthreads();

    // phase B: exclusive scan of cnt[0..512)
    int c0 = cnt[tid * 2], c1 = cnt[tid * 2 + 1];
    part[tid] = c0 + c1;
    __syncthreads();
    for (int off = 1; off < 256; off <<= 1) {
        int t = (tid >= off) ? part[tid - off] : 0;
        __syncthreads();
        part[tid] += t;
        __syncthreads();
    }
    int excl = (tid == 0) ? 0 : part[tid - 1];
    cnt[tid * 2] = excl;
    cnt[tid * 2 + 1] = excl + c0;
    __syncthreads();

    // phase C: place into esrc (cursors bump to inclusive ends)
    for (int p = tid; p < n; p += 256) {
        int e = bk[p];
        int pos = atomicAdd(&cnt[e >> 17], 1);
        esrc[base + pos] = e & 0x1FFFF;
    }
    __syncthreads();

    // phase D: offs[node] = END of node's run
    int lo = r * REGSZ;
#pragma unroll
    for (int i = tid; i < REGSZ; i += 256) {
        int node = lo + i;
        if (node < N) offs[node] = base + cnt[i];
    }
}

// ---------------- gather aggregation (bf16 in, fp32 acc, bf16 out), 4-way ILP
__global__ void gather_agg_kernel(const int* __restrict__ offs, const int* __restrict__ esrc,
                                  const unsigned short* __restrict__ h, unsigned short* __restrict__ agg, int N) {
    int tid = blockIdx.x * 256 + threadIdx.x;
    if (tid >= N * 16) return;
    int node = tid >> 4, c = (tid & 15) * 8;
    int s = (node == 0) ? 0 : offs[node - 1];
    int e = offs[node];
    float acc[8] = {};
    int i = s;
    for (; i + 3 < e; i += 4) {
        int s0 = esrc[i], s1 = esrc[i + 1], s2 = esrc[i + 2], s3 = esrc[i + 3];
        short8 v0 = *(const short8*)&h[(size_t)s0 * H + c];
        short8 v1 = *(const short8*)&h[(size_t)s1 * H + c];
        short8 v2 = *(const short8*)&h[(size_t)s2 * H + c];
        short8 v3 = *(const short8*)&h[(size_t)s3 * H + c];
#pragma unroll
        for (int j = 0; j < 8; ++j)
            acc[j] += (bf2f((unsigned short)v0[j]) + bf2f((unsigned short)v1[j]))
                    + (bf2f((unsigned short)v2[j]) + bf2f((unsigned short)v3[j]));
    }
    for (; i < e; ++i) {
        short8 v0 = *(const short8*)&h[(size_t)esrc[i] * H + c];
#pragma unroll
        for (int j = 0; j < 8; ++j) acc[j] += bf2f((unsigned short)v0[j]);
    }
    short8 o;
#pragma unroll
    for (int j = 0; j < 8; ++j) o[j] = (short)f2bf(acc[j]);
    *(short8*)&agg[(size_t)node * H + c] = o;
}

// ---------------- MFMA GEMM: C = relu((A1 (+A2)) @ Wt^T + bias)
// BM=128 rows, 512 threads = 8 waves (4 row-groups x 2 col-groups), wave = 32 rows x 64 cols.
template <bool HAS_A2>
__global__ __launch_bounds__(512) void gemm_mfma_kernel(
    const unsigned short* __restrict__ A1, const unsigned short* __restrict__ A2,
    const unsigned short* __restrict__ Wt, const float* __restrict__ bias,
    unsigned short* __restrict__ C, int N) {
    __shared__ unsigned short As[128 * H];
    __shared__ unsigned short Ws[H * H];
    int bm = blockIdx.x * 128;
    int tid = threadIdx.x;

#pragma unroll
    for (int rep = 0; rep < 4; ++rep) {
        int lin = rep * 512 + tid;
        int r = lin >> 4, cb = lin & 15;
        int row = bm + r;
        short8 v = {};
        if (row < N) {
            v = *(const short8*)&A1[(size_t)row * H + cb * 8];
            if (HAS_A2) {
                short8 v2 = *(const short8*)&A2[(size_t)row * H + cb * 8];
#pragma unroll
                for (int j = 0; j < 8; ++j)
                    v[j] = (short)f2bf(bf2f((unsigned short)v[j]) + bf2f((unsigned short)v2[j]));
            }
        }
        int byte = r * 256 + ((cb * 16) ^ ((r & 7) << 4));
        *(short8*)((char*)As + byte) = v;
    }
#pragma unroll
    for (int rep = 0; rep < 4; ++rep) {
        int lin = rep * 512 + tid;
        int o = lin >> 4, cb = lin & 15;
        short8 v = *(const short8*)&Wt[(size_t)o * H + cb * 8];
        int byte = o * 256 + ((cb * 16) ^ ((o & 7) << 4));
        *(short8*)((char*)Ws + byte) = v;
    }
    __syncthreads();

    int lane = tid & 63;
    int w = tid >> 6;
    int wr = (w >> 1) * 32;
    int wc = (w & 1) * 64;
    int lrow = lane & 15, kg = lane >> 4;

    short8 a[2][4];
#pragma unroll
    for (int rt = 0; rt < 2; ++rt)
#pragma unroll
        for (int ks = 0; ks < 4; ++ks) {
            int r = wr + rt * 16 + lrow;
            int kb = ks * 64 + kg * 16;
            a[rt][ks] = *(short8*)((char*)As + r * 256 + (kb ^ ((r & 7) << 4)));
        }

    f32x4 acc[2][4] = {};
#pragma unroll
    for (int ct = 0; ct < 4; ++ct) {
#pragma unroll
        for (int ks = 0; ks < 4; ++ks) {
            int o = wc + ct * 16 + lrow;
            int kb = ks * 64 + kg * 16;
            short8 b = *(short8*)((char*)Ws + o * 256 + (kb ^ ((o & 7) << 4)));
            acc[0][ct] = __builtin_amdgcn_mfma_f32_16x16x32_bf16(a[0][ks], b, acc[0][ct], 0, 0, 0);
            acc[1][ct] = __builtin_amdgcn_mfma_f32_16x16x32_bf16(a[1][ks], b, acc[1][ct], 0, 0, 0);
        }
    }

#pragma unroll
    for (int rt = 0; rt < 2; ++rt)
#pragma unroll
        for (int ct = 0; ct < 4; ++ct)
#pragma unroll
            for (int r = 0; r < 4; ++r) {
                int row = bm + wr + rt * 16 + kg * 4 + r;
                int col = wc + ct * 16 + lrow;
                if (row < N) {
                    float v = fmaxf(acc[rt][ct][r] + bias[col], 0.f);
                    C[(size_t)row * H + col] = f2bf(v);
                }
            }
}

// ---------------- graph boundaries
__global__ void find_starts_kernel(const int* __restrict__ batch, int* __restrict__ start, int N, int G) {
    int g = blockIdx.x * 256 + threadIdx.x;
    if (g > G) return;
    if (g == G) { start[G] = N; return; }
    int lo = 0, hi = N;
    while (lo < hi) {
        int mid = (lo + hi) >> 1;
        if (batch[mid] < g) lo = mid + 1; else hi = mid;
    }
    start[g] = lo;
}

// ---------------- mean pool + shared head, one block per graph
__global__ __launch_bounds__(128) void pool_head_kernel(
    const unsigned short* __restrict__ h, const int* __restrict__ start,
    const float* __restrict__ sw, const float* __restrict__ sb,
    const float* __restrict__ ew, const float* __restrict__ eb,
    const float* __restrict__ dw, const float* __restrict__ db,
    float* __restrict__ out, int G) {
    int g = blockIdx.x;
    int j = threadIdx.x;
    int s = start[g], e = start[g + 1];
    float sum = 0.f;
    for (int n = s; n < e; ++n) sum += bf2f(h[(size_t)n * H + j]);
    float cnt = (float)(e - s);
    __shared__ float gm[H];
    gm[j] = sum / fmaxf(cnt, 1.0f);
    __syncthreads();
    float t = sb[j];
    for (int k = 0; k < H; ++k) t += gm[k] * sw[k * H + j];
    t = fmaxf(t, 0.f);
    __shared__ float red[2][H];
    red[0][j] = t * ew[j];
    red[1][j] = t * dw[j];
    __syncthreads();
    for (int off = 64; off > 0; off >>= 1) {
        if (j < off) {
            red[0][j] += red[0][j + off];
            red[1][j] += red[1][j + off];
        }
        __syncthreads();
    }
    if (j == 0) {
        out[g] = red[0][0] + eb[0];
        out[G + g] = red[1][0] + db[0];
    }
}

extern "C" void kernel_launch(void* const* d_in, const int* in_sizes, int n_in,
                              void* d_out, int out_size, void* d_ws, size_t ws_size,
                              hipStream_t stream) {
    const float* x      = (const float*)d_in[0];
    const int*   ei     = (const int*)d_in[1];
    const int*   batch  = (const int*)d_in[2];
    const float* proj_w = (const float*)d_in[3];
    const float* proj_b = (const float*)d_in[4];
    const float* cw1    = (const float*)d_in[5];
    const float* cb1    = (const float*)d_in[6];
    const float* cw2    = (const float*)d_in[7];
    const float* cb2    = (const float*)d_in[8];
    const float* sw     = (const float*)d_in[9];
    const float* sb     = (const float*)d_in[10];
    const float* ew     = (const float*)d_in[11];
    const float* eb     = (const float*)d_in[12];
    const float* dw     = (const float*)d_in[13];
    const float* db     = (const float*)d_in[14];

    int N = in_sizes[0] / 4;
    int E = in_sizes[1] / 2;
    int G = out_size / 2;

    const int* src = ei;
    const int* dst = ei + E;

    unsigned short* h   = (unsigned short*)d_ws;          // N*H bf16
    unsigned short* buf = h + (size_t)N * H;              // N*H bf16 (agg/hidden; bucket overlaps)
    unsigned short* wt  = buf + (size_t)N * H;            // 6*H*H bf16
    int* offs  = (int*)(wt + 6 * H * H);                  // N
    int* rcnt  = offs + N + 1;                            // 256
    int* start = rcnt + 256;                              // G+1
    int* esrc  = start + (G + 1);                         // E
    int* bucket = (int*)buf;                              // nreg*cap ints (free until layer loop)

    float* out = (float*)d_out;

    int nreg = (N + REGSZ - 1) >> 9;                      // 196 for N=100000
    int cap  = (E / nreg) * 5 / 4 + 1024;                 // ample slack for binomial spread

    hipMemsetAsync(rcnt, 0, 256 * sizeof(int), stream);

    // ---- CSR build: partition into region buckets -> per-region local build ----
    partition_kernel<<<(E + PCHUNK - 1) / PCHUNK, 256, 0, stream>>>(src, dst, rcnt, bucket, E, nreg, cap);
    csr_region_kernel<<<nreg, 256, 0, stream>>>(rcnt, bucket, offs, esrc, N, nreg, cap);

    // ---- weights prep + projection ----
    prep_w_kernel<<<(6 * H * H + 255) / 256, 256, 0, stream>>>(cw1, cw2, wt, 6 * H * H);
    proj_kernel<<<(N * 16 + 255) / 256, 256, 0, stream>>>(x, proj_w, proj_b, h, N);

    int gemm_blocks = (N + 127) / 128;
    int gather_blocks = (N * 16 + 255) / 256;

    for (int l = 0; l < 3; ++l) {
        gather_agg_kernel<<<gather_blocks, 256, 0, stream>>>(offs, esrc, h, buf, N);
        gemm_mfma_kernel<true><<<gemm_blocks, 512, 0, stream>>>(
            h, buf, wt + (size_t)l * H * H, cb1 + l * H, buf, N);
        gemm_mfma_kernel<false><<<gemm_blocks, 512, 0, stream>>>(
            buf, nullptr, wt + (size_t)(3 + l) * H * H, cb2 + l * H, h, N);
    }

    find_starts_kernel<<<(G + 1 + 255) / 256, 256, 0, stream>>>(batch, start, N, G);
    pool_head_kernel<<<G, 128, 0, stream>>>(h, start, sw, sb, ew, eb, dw, db, out, G);
}

// Round 9
// 379.801 us; speedup vs baseline: 2.1856x; 1.0671x over previous
//
#include <hip/hip_runtime.h>
#include <hip/hip_bf16.h>

#define H 128
#define REGSZ 512      // nodes per region (power of 2)
#define PCHUNK 4096    // edges per partition block

typedef short short8 __attribute__((ext_vector_type(8)));
typedef float f32x4 __attribute__((ext_vector_type(4)));

__device__ __forceinline__ float bf2f(unsigned short u) {
    union { unsigned int i; float f; } c; c.i = ((unsigned int)u) << 16; return c.f;
}
__device__ __forceinline__ unsigned short f2bf(float f) {
    return __builtin_bit_cast(unsigned short, __float2bfloat16(f));
}

// ---------------- weight prep: wt[m][o][i] = bf16(W_m[i][o])
__global__ void prep_w_kernel(const float* __restrict__ cw1, const float* __restrict__ cw2,
                              unsigned short* __restrict__ wt, int total) {
    int idx = blockIdx.x * 256 + threadIdx.x;
    if (idx >= total) return;
    int m = idx >> 14;
    int o = (idx >> 7) & 127;
    int i = idx & 127;
    const float* srcp = (m < 3) ? (cw1 + (size_t)m * H * H) : (cw2 + (size_t)(m - 3) * H * H);
    wt[idx] = f2bf(srcp[i * H + o]);
}

// ---------------- input projection -> bf16 h
__global__ void proj_kernel(const float* __restrict__ x, const float* __restrict__ pw,
                            const float* __restrict__ pb, unsigned short* __restrict__ hout, int N) {
    int tid = blockIdx.x * 256 + threadIdx.x;
    if (tid >= N * 16) return;
    int i = tid >> 4, c = (tid & 15) * 8;
    float4 xv = *(const float4*)&x[i * 4];
    float acc[8];
#pragma unroll
    for (int j = 0; j < 8; ++j)
        acc[j] = pb[c + j] + xv.x * pw[0 * H + c + j] + xv.y * pw[1 * H + c + j]
               + xv.z * pw[2 * H + c + j] + xv.w * pw[3 * H + c + j];
    short8 o;
#pragma unroll
    for (int j = 0; j < 8; ++j) o[j] = (short)f2bf(acc[j]);
    *(short8*)&hout[(size_t)i * H + c] = o;
}

// ================= CSR build =================
// bucket entry: (dstLocal << 17) | src   (dstLocal < 512, src < 2^17)
__global__ __launch_bounds__(256) void partition_kernel(
    const int* __restrict__ src, const int* __restrict__ dst,
    int* __restrict__ rcnt, int* __restrict__ bucket,
    int E, int nreg, int cap) {
    __shared__ int hcnt[256];
    __shared__ int hbase[256];
    int tid = threadIdx.x;
    hcnt[tid] = 0;
    __syncthreads();
    int e0 = blockIdx.x * PCHUNK;
    int e1 = min(e0 + PCHUNK, E);
    for (int e = e0 + tid; e < e1; e += 256)
        atomicAdd(&hcnt[dst[e] >> 9], 1);
    __syncthreads();
    {
        int c = hcnt[tid];
        hbase[tid] = (c > 0) ? atomicAdd(&rcnt[tid], c) : 0;
        hcnt[tid] = 0;
    }
    __syncthreads();
    for (int e = e0 + tid; e < e1; e += 256) {
        int d = dst[e], s = src[e];
        int r = d >> 9;
        int pos = hbase[r] + atomicAdd(&hcnt[r], 1);
        if (pos < cap) bucket[(size_t)r * cap + pos] = ((d & (REGSZ - 1)) << 17) | s;
    }
}

// one block per region: local histogram -> LDS scan -> place -> write offs ends.
__global__ __launch_bounds__(256) void csr_region_kernel(
    const int* __restrict__ rcnt, const int* __restrict__ bucket,
    int* __restrict__ offs, int* __restrict__ esrc,
    int N, int nreg, int cap) {
    __shared__ int cnt[REGSZ];
    __shared__ int part[256];
    __shared__ int sbase;
    int r = blockIdx.x;
    int tid = threadIdx.x;

    int v = (tid < nreg) ? rcnt[tid] : 0;
    part[tid] = v;
    __syncthreads();
    for (int off = 1; off < 256; off <<= 1) {
        int t = (tid >= off) ? part[tid - off] : 0;
        __syncthreads();
        part[tid] += t;
        __syncthreads();
    }
    if (tid == 0) sbase = (r == 0) ? 0 : part[r - 1];
    cnt[tid] = 0;
    cnt[tid + 256] = 0;
    __syncthreads();
    int base = sbase;
    int n = min(part[r] - base, cap);
    const int* bk = bucket + (size_t)r * cap;

    for (int p = tid; p < n; p += 256)
        atomicAdd(&cnt[bk[p] >> 17], 1);
    __syncthreads();

    int c0 = cnt[tid * 2], c1 = cnt[tid * 2 + 1];
    part[tid] = c0 + c1;
    __syncthreads();
    for (int off = 1; off < 256; off <<= 1) {
        int t = (tid >= off) ? part[tid - off] : 0;
        __syncthreads();
        part[tid] += t;
        __syncthreads();
    }
    int excl = (tid == 0) ? 0 : part[tid - 1];
    cnt[tid * 2] = excl;
    cnt[tid * 2 + 1] = excl + c0;
    __syncthreads();

    for (int p = tid; p < n; p += 256) {
        int e = bk[p];
        int pos = atomicAdd(&cnt[e >> 17], 1);
        esrc[base + pos] = e & 0x1FFFF;
    }
    __syncthreads();

    int lo = r * REGSZ;
#pragma unroll
    for (int i = tid; i < REGSZ; i += 256) {
        int node = lo + i;
        if (node < N) offs[node] = base + cnt[i];
    }
}

// ---------------- gather aggregation (bf16 in, fp32 acc, bf16 out), 8-way ILP
__global__ void gather_agg_kernel(const int* __restrict__ offs, const int* __restrict__ esrc,
                                  const unsigned short* __restrict__ h, unsigned short* __restrict__ agg, int N) {
    int tid = blockIdx.x * 256 + threadIdx.x;
    if (tid >= N * 16) return;
    int node = tid >> 4, c = (tid & 15) * 8;
    int s = (node == 0) ? 0 : offs[node - 1];
    int e = offs[node];
    float acc[8] = {};
    int i = s;
    for (; i + 7 < e; i += 8) {
        short8 v[8];
#pragma unroll
        for (int k = 0; k < 8; ++k) v[k] = *(const short8*)&h[(size_t)esrc[i + k] * H + c];
#pragma unroll
        for (int j = 0; j < 8; ++j) {
            float t0 = bf2f((unsigned short)v[0][j]) + bf2f((unsigned short)v[1][j]);
            float t1 = bf2f((unsigned short)v[2][j]) + bf2f((unsigned short)v[3][j]);
            float t2 = bf2f((unsigned short)v[4][j]) + bf2f((unsigned short)v[5][j]);
            float t3 = bf2f((unsigned short)v[6][j]) + bf2f((unsigned short)v[7][j]);
            acc[j] += (t0 + t1) + (t2 + t3);
        }
    }
    for (; i + 3 < e; i += 4) {
        short8 v[4];
#pragma unroll
        for (int k = 0; k < 4; ++k) v[k] = *(const short8*)&h[(size_t)esrc[i + k] * H + c];
#pragma unroll
        for (int j = 0; j < 8; ++j)
            acc[j] += (bf2f((unsigned short)v[0][j]) + bf2f((unsigned short)v[1][j]))
                    + (bf2f((unsigned short)v[2][j]) + bf2f((unsigned short)v[3][j]));
    }
    for (; i < e; ++i) {
        short8 v0 = *(const short8*)&h[(size_t)esrc[i] * H + c];
#pragma unroll
        for (int j = 0; j < 8; ++j) acc[j] += bf2f((unsigned short)v0[j]);
    }
    short8 o;
#pragma unroll
    for (int j = 0; j < 8; ++j) o[j] = (short)f2bf(acc[j]);
    *(short8*)&agg[(size_t)node * H + c] = o;
}

// ---------------- fused GIN MLP: h = relu( relu((h+agg)@W1t^T+b1) @ W2t^T + b2 )
// BM=128 rows, 512 threads = 8 waves (4 row-groups x 2 col-groups), wave = 32 rows x 64 cols.
// m is re-staged through the As LDS buffer between the two MFMA passes.
__global__ __launch_bounds__(512) void fused_mlp_kernel(
    const unsigned short* __restrict__ A1, const unsigned short* __restrict__ A2,
    const unsigned short* __restrict__ W1t, const unsigned short* __restrict__ W2t,
    const float* __restrict__ b1, const float* __restrict__ b2,
    unsigned short* __restrict__ C, int N) {
    __shared__ unsigned short As[128 * H];   // 32KB
    __shared__ unsigned short Ws1[H * H];    // 32KB
    __shared__ unsigned short Ws2[H * H];    // 32KB
    int bm = blockIdx.x * 128;
    int tid = threadIdx.x;

    // stage A = bf16(h + agg)
#pragma unroll
    for (int rep = 0; rep < 4; ++rep) {
        int lin = rep * 512 + tid;
        int r = lin >> 4, cb = lin & 15;
        int row = bm + r;
        short8 vv = {};
        if (row < N) {
            vv = *(const short8*)&A1[(size_t)row * H + cb * 8];
            short8 v2 = *(const short8*)&A2[(size_t)row * H + cb * 8];
#pragma unroll
            for (int j = 0; j < 8; ++j)
                vv[j] = (short)f2bf(bf2f((unsigned short)vv[j]) + bf2f((unsigned short)v2[j]));
        }
        int byte = r * 256 + ((cb * 16) ^ ((r & 7) << 4));
        *(short8*)((char*)As + byte) = vv;
    }
    // stage W1, W2
#pragma unroll
    for (int rep = 0; rep < 4; ++rep) {
        int lin = rep * 512 + tid;
        int o = lin >> 4, cb = lin & 15;
        int byte = o * 256 + ((cb * 16) ^ ((o & 7) << 4));
        *(short8*)((char*)Ws1 + byte) = *(const short8*)&W1t[(size_t)o * H + cb * 8];
        *(short8*)((char*)Ws2 + byte) = *(const short8*)&W2t[(size_t)o * H + cb * 8];
    }
    __syncthreads();

    int lane = tid & 63;
    int w = tid >> 6;
    int wr = (w >> 1) * 32;
    int wc = (w & 1) * 64;
    int lrow = lane & 15, kg = lane >> 4;

    float b1v[4], b2v[4];
#pragma unroll
    for (int ct = 0; ct < 4; ++ct) {
        b1v[ct] = b1[wc + ct * 16 + lrow];
        b2v[ct] = b2[wc + ct * 16 + lrow];
    }

    short8 a[2][4];
#pragma unroll
    for (int rt = 0; rt < 2; ++rt)
#pragma unroll
        for (int ks = 0; ks < 4; ++ks) {
            int r = wr + rt * 16 + lrow;
            int kb = ks * 64 + kg * 16;
            a[rt][ks] = *(short8*)((char*)As + r * 256 + (kb ^ ((r & 7) << 4)));
        }

    f32x4 acc[2][4] = {};
#pragma unroll
    for (int ct = 0; ct < 4; ++ct) {
#pragma unroll
        for (int ks = 0; ks < 4; ++ks) {
            int o = wc + ct * 16 + lrow;
            int kb = ks * 64 + kg * 16;
            short8 b = *(short8*)((char*)Ws1 + o * 256 + (kb ^ ((o & 7) << 4)));
            acc[0][ct] = __builtin_amdgcn_mfma_f32_16x16x32_bf16(a[0][ks], b, acc[0][ct], 0, 0, 0);
            acc[1][ct] = __builtin_amdgcn_mfma_f32_16x16x32_bf16(a[1][ks], b, acc[1][ct], 0, 0, 0);
        }
    }
    __syncthreads();   // everyone done reading As (a-frags are in regs)

    // write m = relu(acc + b1) back into As (bf16, swizzle-consistent)
#pragma unroll
    for (int rt = 0; rt < 2; ++rt)
#pragma unroll
        for (int ct = 0; ct < 4; ++ct)
#pragma unroll
            for (int rr = 0; rr < 4; ++rr) {
                int r = wr + rt * 16 + kg * 4 + rr;
                int col = wc + ct * 16 + lrow;
                float v = fmaxf(acc[rt][ct][rr] + b1v[ct], 0.f);
                int byte = r * 256 + ((col * 2) ^ ((r & 7) << 4));
                *(unsigned short*)((char*)As + byte) = f2bf(v);
            }
    __syncthreads();

    // second GEMM: m @ W2
#pragma unroll
    for (int rt = 0; rt < 2; ++rt)
#pragma unroll
        for (int ks = 0; ks < 4; ++ks) {
            int r = wr + rt * 16 + lrow;
            int kb = ks * 64 + kg * 16;
            a[rt][ks] = *(short8*)((char*)As + r * 256 + (kb ^ ((r & 7) << 4)));
        }

    f32x4 acc2[2][4] = {};
#pragma unroll
    for (int ct = 0; ct < 4; ++ct) {
#pragma unroll
        for (int ks = 0; ks < 4; ++ks) {
            int o = wc + ct * 16 + lrow;
            int kb = ks * 64 + kg * 16;
            short8 b = *(short8*)((char*)Ws2 + o * 256 + (kb ^ ((o & 7) << 4)));
            acc2[0][ct] = __builtin_amdgcn_mfma_f32_16x16x32_bf16(a[0][ks], b, acc2[0][ct], 0, 0, 0);
            acc2[1][ct] = __builtin_amdgcn_mfma_f32_16x16x32_bf16(a[1][ks], b, acc2[1][ct], 0, 0, 0);
        }
    }

#pragma unroll
    for (int rt = 0; rt < 2; ++rt)
#pragma unroll
        for (int ct = 0; ct < 4; ++ct)
#pragma unroll
            for (int rr = 0; rr < 4; ++rr) {
                int row = bm + wr + rt * 16 + kg * 4 + rr;
                int col = wc + ct * 16 + lrow;
                if (row < N) {
                    float v = fmaxf(acc2[rt][ct][rr] + b2v[ct], 0.f);
                    C[(size_t)row * H + col] = f2bf(v);
                }
            }
}

// ---------------- graph boundaries
__global__ void find_starts_kernel(const int* __restrict__ batch, int* __restrict__ start, int N, int G) {
    int g = blockIdx.x * 256 + threadIdx.x;
    if (g > G) return;
    if (g == G) { start[G] = N; return; }
    int lo = 0, hi = N;
    while (lo < hi) {
        int mid = (lo + hi) >> 1;
        if (batch[mid] < g) lo = mid + 1; else hi = mid;
    }
    start[g] = lo;
}

// ---------------- mean pool + shared head, one block per graph
__global__ __launch_bounds__(128) void pool_head_kernel(
    const unsigned short* __restrict__ h, const int* __restrict__ start,
    const float* __restrict__ sw, const float* __restrict__ sb,
    const float* __restrict__ ew, const float* __restrict__ eb,
    const float* __restrict__ dw, const float* __restrict__ db,
    float* __restrict__ out, int G) {
    int g = blockIdx.x;
    int j = threadIdx.x;
    int s = start[g], e = start[g + 1];
    float sum = 0.f;
    for (int n = s; n < e; ++n) sum += bf2f(h[(size_t)n * H + j]);
    float cnt = (float)(e - s);
    __shared__ float gm[H];
    gm[j] = sum / fmaxf(cnt, 1.0f);
    __syncthreads();
    float t = sb[j];
    for (int k = 0; k < H; ++k) t += gm[k] * sw[k * H + j];
    t = fmaxf(t, 0.f);
    __shared__ float red[2][H];
    red[0][j] = t * ew[j];
    red[1][j] = t * dw[j];
    __syncthreads();
    for (int off = 64; off > 0; off >>= 1) {
        if (j < off) {
            red[0][j] += red[0][j + off];
            red[1][j] += red[1][j + off];
        }
        __syncthreads();
    }
    if (j == 0) {
        out[g] = red[0][0] + eb[0];
        out[G + g] = red[1][0] + db[0];
    }
}

extern "C" void kernel_launch(void* const* d_in, const int* in_sizes, int n_in,
                              void* d_out, int out_size, void* d_ws, size_t ws_size,
                              hipStream_t stream) {
    const float* x      = (const float*)d_in[0];
    const int*   ei     = (const int*)d_in[1];
    const int*   batch  = (const int*)d_in[2];
    const float* proj_w = (const float*)d_in[3];
    const float* proj_b = (const float*)d_in[4];
    const float* cw1    = (const float*)d_in[5];
    const float* cb1    = (const float*)d_in[6];
    const float* cw2    = (const float*)d_in[7];
    const float* cb2    = (const float*)d_in[8];
    const float* sw     = (const float*)d_in[9];
    const float* sb     = (const float*)d_in[10];
    const float* ew     = (const float*)d_in[11];
    const float* eb     = (const float*)d_in[12];
    const float* dw     = (const float*)d_in[13];
    const float* db     = (const float*)d_in[14];

    int N = in_sizes[0] / 4;
    int E = in_sizes[1] / 2;
    int G = out_size / 2;

    const int* src = ei;
    const int* dst = ei + E;

    unsigned short* h   = (unsigned short*)d_ws;          // N*H bf16
    unsigned short* buf = h + (size_t)N * H;              // N*H bf16 (agg; bucket overlaps)
    unsigned short* wt  = buf + (size_t)N * H;            // 6*H*H bf16
    int* offs  = (int*)(wt + 6 * H * H);                  // N
    int* rcnt  = offs + N + 1;                            // 256
    int* start = rcnt + 256;                              // G+1
    int* esrc  = start + (G + 1);                         // E
    int* bucket = (int*)buf;                              // nreg*cap ints (free until layer loop)

    float* out = (float*)d_out;

    int nreg = (N + REGSZ - 1) >> 9;                      // 196 for N=100000
    int cap  = (E / nreg) * 5 / 4 + 1024;

    hipMemsetAsync(rcnt, 0, 256 * sizeof(int), stream);

    // ---- CSR build: partition into region buckets -> per-region local build ----
    partition_kernel<<<(E + PCHUNK - 1) / PCHUNK, 256, 0, stream>>>(src, dst, rcnt, bucket, E, nreg, cap);
    csr_region_kernel<<<nreg, 256, 0, stream>>>(rcnt, bucket, offs, esrc, N, nreg, cap);

    // ---- weights prep + projection ----
    prep_w_kernel<<<(6 * H * H + 255) / 256, 256, 0, stream>>>(cw1, cw2, wt, 6 * H * H);
    proj_kernel<<<(N * 16 + 255) / 256, 256, 0, stream>>>(x, proj_w, proj_b, h, N);

    int mlp_blocks = (N + 127) / 128;
    int gather_blocks = (N * 16 + 255) / 256;

    for (int l = 0; l < 3; ++l) {
        gather_agg_kernel<<<gather_blocks, 256, 0, stream>>>(offs, esrc, h, buf, N);
        fused_mlp_kernel<<<mlp_blocks, 512, 0, stream>>>(
            h, buf, wt + (size_t)l * H * H, wt + (size_t)(3 + l) * H * H,
            cb1 + l * H, cb2 + l * H, h, N);
    }

    find_starts_kernel<<<(G + 1 + 255) / 256, 256, 0, stream>>>(batch, start, N, G);
    pool_head_kernel<<<G, 128, 0, stream>>>(h, start, sw, sb, ew, eb, dw, db, out, G);
}

// Round 10
// 353.061 us; speedup vs baseline: 2.3512x; 1.0757x over previous
//
#include <hip/hip_runtime.h>
#include <hip/hip_bf16.h>

#define H 128
#define REGSZ 512      // nodes per region (power of 2)
#define PCHUNK 4096    // edges per partition block

typedef short short8 __attribute__((ext_vector_type(8)));
typedef float f32x4 __attribute__((ext_vector_type(4)));

__device__ __forceinline__ float bf2f(unsigned short u) {
    union { unsigned int i; float f; } c; c.i = ((unsigned int)u) << 16; return c.f;
}
__device__ __forceinline__ unsigned short f2bf(float f) {
    return __builtin_bit_cast(unsigned short, __float2bfloat16(f));
}
// pack 8 floats -> 8 fp8(e4m3) bytes
__device__ __forceinline__ uint2 pack_fp8x8(const float* f) {
    unsigned int lo = 0, hi = 0;
    lo = __builtin_amdgcn_cvt_pk_fp8_f32(f[0], f[1], lo, 0);
    lo = __builtin_amdgcn_cvt_pk_fp8_f32(f[2], f[3], lo, 1);
    hi = __builtin_amdgcn_cvt_pk_fp8_f32(f[4], f[5], hi, 0);
    hi = __builtin_amdgcn_cvt_pk_fp8_f32(f[6], f[7], hi, 1);
    return make_uint2(lo, hi);
}

// ---------------- weight prep: wt[m][o][i] = bf16(W_m[i][o])
__global__ void prep_w_kernel(const float* __restrict__ cw1, const float* __restrict__ cw2,
                              unsigned short* __restrict__ wt, int total) {
    int idx = blockIdx.x * 256 + threadIdx.x;
    if (idx >= total) return;
    int m = idx >> 14;
    int o = (idx >> 7) & 127;
    int i = idx & 127;
    const float* srcp = (m < 3) ? (cw1 + (size_t)m * H * H) : (cw2 + (size_t)(m - 3) * H * H);
    wt[idx] = f2bf(srcp[i * H + o]);
}

// ---------------- input projection -> bf16 h + fp8 h8
__global__ void proj_kernel(const float* __restrict__ x, const float* __restrict__ pw,
                            const float* __restrict__ pb, unsigned short* __restrict__ hout,
                            unsigned char* __restrict__ h8, int N) {
    int tid = blockIdx.x * 256 + threadIdx.x;
    if (tid >= N * 16) return;
    int i = tid >> 4, c = (tid & 15) * 8;
    float4 xv = *(const float4*)&x[i * 4];
    float acc[8];
#pragma unroll
    for (int j = 0; j < 8; ++j)
        acc[j] = pb[c + j] + xv.x * pw[0 * H + c + j] + xv.y * pw[1 * H + c + j]
               + xv.z * pw[2 * H + c + j] + xv.w * pw[3 * H + c + j];
    short8 o;
#pragma unroll
    for (int j = 0; j < 8; ++j) o[j] = (short)f2bf(acc[j]);
    *(short8*)&hout[(size_t)i * H + c] = o;
    *(uint2*)&h8[(size_t)i * H + c] = pack_fp8x8(acc);
}

// ================= CSR build =================
// bucket entry: (dstLocal << 17) | src   (dstLocal < 512, src < 2^17)
__global__ __launch_bounds__(256) void partition_kernel(
    const int* __restrict__ src, const int* __restrict__ dst,
    int* __restrict__ rcnt, int* __restrict__ bucket,
    int E, int nreg, int cap) {
    __shared__ int hcnt[256];
    __shared__ int hbase[256];
    int tid = threadIdx.x;
    hcnt[tid] = 0;
    __syncthreads();
    int e0 = blockIdx.x * PCHUNK;
    int e1 = min(e0 + PCHUNK, E);
    for (int e = e0 + tid; e < e1; e += 256)
        atomicAdd(&hcnt[dst[e] >> 9], 1);
    __syncthreads();
    {
        int c = hcnt[tid];
        hbase[tid] = (c > 0) ? atomicAdd(&rcnt[tid], c) : 0;
        hcnt[tid] = 0;
    }
    __syncthreads();
    for (int e = e0 + tid; e < e1; e += 256) {
        int d = dst[e], s = src[e];
        int r = d >> 9;
        int pos = hbase[r] + atomicAdd(&hcnt[r], 1);
        if (pos < cap) bucket[(size_t)r * cap + pos] = ((d & (REGSZ - 1)) << 17) | s;
    }
}

// one block per region: local histogram -> LDS scan -> place -> write offs ends.
__global__ __launch_bounds__(256) void csr_region_kernel(
    const int* __restrict__ rcnt, const int* __restrict__ bucket,
    int* __restrict__ offs, int* __restrict__ esrc,
    int N, int nreg, int cap) {
    __shared__ int cnt[REGSZ];
    __shared__ int part[256];
    __shared__ int sbase;
    int r = blockIdx.x;
    int tid = threadIdx.x;

    int v = (tid < nreg) ? rcnt[tid] : 0;
    part[tid] = v;
    __syncthreads();
    for (int off = 1; off < 256; off <<= 1) {
        int t = (tid >= off) ? part[tid - off] : 0;
        __syncthreads();
        part[tid] += t;
        __syncthreads();
    }
    if (tid == 0) sbase = (r == 0) ? 0 : part[r - 1];
    cnt[tid] = 0;
    cnt[tid + 256] = 0;
    __syncthreads();
    int base = sbase;
    int n = min(part[r] - base, cap);
    const int* bk = bucket + (size_t)r * cap;

    for (int p = tid; p < n; p += 256)
        atomicAdd(&cnt[bk[p] >> 17], 1);
    __syncthreads();

    int c0 = cnt[tid * 2], c1 = cnt[tid * 2 + 1];
    part[tid] = c0 + c1;
    __syncthreads();
    for (int off = 1; off < 256; off <<= 1) {
        int t = (tid >= off) ? part[tid - off] : 0;
        __syncthreads();
        part[tid] += t;
        __syncthreads();
    }
    int excl = (tid == 0) ? 0 : part[tid - 1];
    cnt[tid * 2] = excl;
    cnt[tid * 2 + 1] = excl + c0;
    __syncthreads();

    for (int p = tid; p < n; p += 256) {
        int e = bk[p];
        int pos = atomicAdd(&cnt[e >> 17], 1);
        esrc[base + pos] = e & 0x1FFFF;
    }
    __syncthreads();

    int lo = r * REGSZ;
#pragma unroll
    for (int i = tid; i < REGSZ; i += 256) {
        int node = lo + i;
        if (node < N) offs[node] = base + cnt[i];
    }
}

// ---------------- gather aggregation (fp8 in, fp32 acc, bf16 out), 4-way ILP
__global__ void gather_agg_kernel(const int* __restrict__ offs, const int* __restrict__ esrc,
                                  const unsigned char* __restrict__ h8, unsigned short* __restrict__ agg, int N) {
    int tid = blockIdx.x * 256 + threadIdx.x;
    if (tid >= N * 16) return;
    int node = tid >> 4, c = (tid & 15) * 8;
    int s = (node == 0) ? 0 : offs[node - 1];
    int e = offs[node];
    float acc[8] = {};
    int i = s;
    for (; i + 3 < e; i += 4) {
        uint2 v[4];
#pragma unroll
        for (int k = 0; k < 4; ++k) v[k] = *(const uint2*)&h8[(size_t)esrc[i + k] * H + c];
#pragma unroll
        for (int k = 0; k < 4; ++k) {
            acc[0] += __builtin_amdgcn_cvt_f32_fp8(v[k].x, 0);
            acc[1] += __builtin_amdgcn_cvt_f32_fp8(v[k].x, 1);
            acc[2] += __builtin_amdgcn_cvt_f32_fp8(v[k].x, 2);
            acc[3] += __builtin_amdgcn_cvt_f32_fp8(v[k].x, 3);
            acc[4] += __builtin_amdgcn_cvt_f32_fp8(v[k].y, 0);
            acc[5] += __builtin_amdgcn_cvt_f32_fp8(v[k].y, 1);
            acc[6] += __builtin_amdgcn_cvt_f32_fp8(v[k].y, 2);
            acc[7] += __builtin_amdgcn_cvt_f32_fp8(v[k].y, 3);
        }
    }
    for (; i < e; ++i) {
        uint2 v = *(const uint2*)&h8[(size_t)esrc[i] * H + c];
        acc[0] += __builtin_amdgcn_cvt_f32_fp8(v.x, 0);
        acc[1] += __builtin_amdgcn_cvt_f32_fp8(v.x, 1);
        acc[2] += __builtin_amdgcn_cvt_f32_fp8(v.x, 2);
        acc[3] += __builtin_amdgcn_cvt_f32_fp8(v.x, 3);
        acc[4] += __builtin_amdgcn_cvt_f32_fp8(v.y, 0);
        acc[5] += __builtin_amdgcn_cvt_f32_fp8(v.y, 1);
        acc[6] += __builtin_amdgcn_cvt_f32_fp8(v.y, 2);
        acc[7] += __builtin_amdgcn_cvt_f32_fp8(v.y, 3);
    }
    short8 o;
#pragma unroll
    for (int j = 0; j < 8; ++j) o[j] = (short)f2bf(acc[j]);
    *(short8*)&agg[(size_t)node * H + c] = o;
}

// ---------------- fused GIN MLP: h = relu( relu((h+agg)@W1t^T+b1) @ W2t^T + b2 ), + fp8 mirror
// BM=128 rows, 512 threads = 8 waves; m and the output are re-staged through As LDS.
__global__ __launch_bounds__(512) void fused_mlp_kernel(
    const unsigned short* __restrict__ A1, const unsigned short* __restrict__ A2,
    const unsigned short* __restrict__ W1t, const unsigned short* __restrict__ W2t,
    const float* __restrict__ b1, const float* __restrict__ b2,
    unsigned short* __restrict__ C, unsigned char* __restrict__ h8, int N) {
    __shared__ unsigned short As[128 * H];   // 32KB
    __shared__ unsigned short Ws1[H * H];    // 32KB
    __shared__ unsigned short Ws2[H * H];    // 32KB
    int bm = blockIdx.x * 128;
    int tid = threadIdx.x;

    // stage A = bf16(h + agg), swizzled
#pragma unroll
    for (int rep = 0; rep < 4; ++rep) {
        int lin = rep * 512 + tid;
        int r = lin >> 4, cb = lin & 15;
        int row = bm + r;
        short8 vv = {};
        if (row < N) {
            vv = *(const short8*)&A1[(size_t)row * H + cb * 8];
            short8 v2 = *(const short8*)&A2[(size_t)row * H + cb * 8];
#pragma unroll
            for (int j = 0; j < 8; ++j)
                vv[j] = (short)f2bf(bf2f((unsigned short)vv[j]) + bf2f((unsigned short)v2[j]));
        }
        int byte = r * 256 + ((cb * 16) ^ ((r & 7) << 4));
        *(short8*)((char*)As + byte) = vv;
    }
#pragma unroll
    for (int rep = 0; rep < 4; ++rep) {
        int lin = rep * 512 + tid;
        int o = lin >> 4, cb = lin & 15;
        int byte = o * 256 + ((cb * 16) ^ ((o & 7) << 4));
        *(short8*)((char*)Ws1 + byte) = *(const short8*)&W1t[(size_t)o * H + cb * 8];
        *(short8*)((char*)Ws2 + byte) = *(const short8*)&W2t[(size_t)o * H + cb * 8];
    }
    __syncthreads();

    int lane = tid & 63;
    int w = tid >> 6;
    int wr = (w >> 1) * 32;
    int wc = (w & 1) * 64;
    int lrow = lane & 15, kg = lane >> 4;

    float b1v[4], b2v[4];
#pragma unroll
    for (int ct = 0; ct < 4; ++ct) {
        b1v[ct] = b1[wc + ct * 16 + lrow];
        b2v[ct] = b2[wc + ct * 16 + lrow];
    }

    short8 a[2][4];
#pragma unroll
    for (int rt = 0; rt < 2; ++rt)
#pragma unroll
        for (int ks = 0; ks < 4; ++ks) {
            int r = wr + rt * 16 + lrow;
            int kb = ks * 64 + kg * 16;
            a[rt][ks] = *(short8*)((char*)As + r * 256 + (kb ^ ((r & 7) << 4)));
        }

    f32x4 acc[2][4] = {};
#pragma unroll
    for (int ct = 0; ct < 4; ++ct) {
#pragma unroll
        for (int ks = 0; ks < 4; ++ks) {
            int o = wc + ct * 16 + lrow;
            int kb = ks * 64 + kg * 16;
            short8 b = *(short8*)((char*)Ws1 + o * 256 + (kb ^ ((o & 7) << 4)));
            acc[0][ct] = __builtin_amdgcn_mfma_f32_16x16x32_bf16(a[0][ks], b, acc[0][ct], 0, 0, 0);
            acc[1][ct] = __builtin_amdgcn_mfma_f32_16x16x32_bf16(a[1][ks], b, acc[1][ct], 0, 0, 0);
        }
    }
    __syncthreads();   // all As reads done

    // write m = relu(acc + b1) back into As (bf16, swizzle-consistent)
#pragma unroll
    for (int rt = 0; rt < 2; ++rt)
#pragma unroll
        for (int ct = 0; ct < 4; ++ct)
#pragma unroll
            for (int rr = 0; rr < 4; ++rr) {
                int r = wr + rt * 16 + kg * 4 + rr;
                int col = wc + ct * 16 + lrow;
                float v = fmaxf(acc[rt][ct][rr] + b1v[ct], 0.f);
                int byte = r * 256 + ((col * 2) ^ ((r & 7) << 4));
                *(unsigned short*)((char*)As + byte) = f2bf(v);
            }
    __syncthreads();

    // second GEMM: m @ W2
#pragma unroll
    for (int rt = 0; rt < 2; ++rt)
#pragma unroll
        for (int ks = 0; ks < 4; ++ks) {
            int r = wr + rt * 16 + lrow;
            int kb = ks * 64 + kg * 16;
            a[rt][ks] = *(short8*)((char*)As + r * 256 + (kb ^ ((r & 7) << 4)));
        }

    f32x4 acc2[2][4] = {};
#pragma unroll
    for (int ct = 0; ct < 4; ++ct) {
#pragma unroll
        for (int ks = 0; ks < 4; ++ks) {
            int o = wc + ct * 16 + lrow;
            int kb = ks * 64 + kg * 16;
            short8 b = *(short8*)((char*)Ws2 + o * 256 + (kb ^ ((o & 7) << 4)));
            acc2[0][ct] = __builtin_amdgcn_mfma_f32_16x16x32_bf16(a[0][ks], b, acc2[0][ct], 0, 0, 0);
            acc2[1][ct] = __builtin_amdgcn_mfma_f32_16x16x32_bf16(a[1][ks], b, acc2[1][ct], 0, 0, 0);
        }
    }
    __syncthreads();   // all As reads done; now reuse As as epilogue staging (LINEAR layout)

    // stage output = relu(acc2 + b2) into As, linear row-major
#pragma unroll
    for (int rt = 0; rt < 2; ++rt)
#pragma unroll
        for (int ct = 0; ct < 4; ++ct)
#pragma unroll
            for (int rr = 0; rr < 4; ++rr) {
                int r = wr + rt * 16 + kg * 4 + rr;
                int col = wc + ct * 16 + lrow;
                float v = fmaxf(acc2[rt][ct][rr] + b2v[ct], 0.f);
                As[r * H + col] = f2bf(v);
            }
    __syncthreads();

    // cooperative vectorized writeout: bf16 h + fp8 h8
#pragma unroll
    for (int rep = 0; rep < 4; ++rep) {
        int lin = rep * 512 + tid;
        int r = lin >> 4, cb = lin & 15;
        int row = bm + r;
        if (row < N) {
            short8 v = *(short8*)&As[r * H + cb * 8];
            *(short8*)&C[(size_t)row * H + cb * 8] = v;
            float f[8];
#pragma unroll
            for (int j = 0; j < 8; ++j) f[j] = bf2f((unsigned short)v[j]);
            *(uint2*)&h8[(size_t)row * H + cb * 8] = pack_fp8x8(f);
        }
    }
}

// ---------------- mean pool + shared head, one block per graph (inline boundary search)
__global__ __launch_bounds__(128) void pool_head_kernel(
    const unsigned short* __restrict__ h, const int* __restrict__ batch,
    const float* __restrict__ sw, const float* __restrict__ sb,
    const float* __restrict__ ew, const float* __restrict__ eb,
    const float* __restrict__ dw, const float* __restrict__ db,
    float* __restrict__ out, int N, int G) {
    int g = blockIdx.x;
    int j = threadIdx.x;
    // lower_bound(batch, g) and lower_bound(batch, g+1), all threads redundantly
    int s, e;
    {
        int lo = 0, hi = N;
        while (lo < hi) { int mid = (lo + hi) >> 1; if (batch[mid] < g) lo = mid + 1; else hi = mid; }
        s = lo;
        hi = N;
        while (lo < hi) { int mid = (lo + hi) >> 1; if (batch[mid] < g + 1) lo = mid + 1; else hi = mid; }
        e = lo;
    }
    float sum = 0.f;
    for (int n = s; n < e; ++n) sum += bf2f(h[(size_t)n * H + j]);
    float cnt = (float)(e - s);
    __shared__ float gm[H];
    gm[j] = sum / fmaxf(cnt, 1.0f);
    __syncthreads();
    float t = sb[j];
    for (int k = 0; k < H; ++k) t += gm[k] * sw[k * H + j];
    t = fmaxf(t, 0.f);
    __shared__ float red[2][H];
    red[0][j] = t * ew[j];
    red[1][j] = t * dw[j];
    __syncthreads();
    for (int off = 64; off > 0; off >>= 1) {
        if (j < off) {
            red[0][j] += red[0][j + off];
            red[1][j] += red[1][j + off];
        }
        __syncthreads();
    }
    if (j == 0) {
        out[g] = red[0][0] + eb[0];
        out[G + g] = red[1][0] + db[0];
    }
}

extern "C" void kernel_launch(void* const* d_in, const int* in_sizes, int n_in,
                              void* d_out, int out_size, void* d_ws, size_t ws_size,
                              hipStream_t stream) {
    const float* x      = (const float*)d_in[0];
    const int*   ei     = (const int*)d_in[1];
    const int*   batch  = (const int*)d_in[2];
    const float* proj_w = (const float*)d_in[3];
    const float* proj_b = (const float*)d_in[4];
    const float* cw1    = (const float*)d_in[5];
    const float* cb1    = (const float*)d_in[6];
    const float* cw2    = (const float*)d_in[7];
    const float* cb2    = (const float*)d_in[8];
    const float* sw     = (const float*)d_in[9];
    const float* sb     = (const float*)d_in[10];
    const float* ew     = (const float*)d_in[11];
    const float* eb     = (const float*)d_in[12];
    const float* dw     = (const float*)d_in[13];
    const float* db     = (const float*)d_in[14];

    int N = in_sizes[0] / 4;
    int E = in_sizes[1] / 2;
    int G = out_size / 2;

    const int* src = ei;
    const int* dst = ei + E;

    unsigned short* h   = (unsigned short*)d_ws;          // N*H bf16
    unsigned short* buf = h + (size_t)N * H;              // N*H bf16 (agg; bucket overlaps)
    unsigned short* wt  = buf + (size_t)N * H;            // 6*H*H bf16
    int* offs  = (int*)(wt + 6 * H * H);                  // N
    int* rcnt  = offs + N + 1;                            // 256
    int* esrc  = rcnt + 256;                              // E
    unsigned char* h8 = (unsigned char*)(esrc + E);       // N*H fp8
    int* bucket = (int*)buf;                              // nreg*cap ints (free until layer loop)

    float* out = (float*)d_out;

    int nreg = (N + REGSZ - 1) >> 9;                      // 196 for N=100000
    int cap  = (E / nreg) * 5 / 4 + 1024;

    hipMemsetAsync(rcnt, 0, 256 * sizeof(int), stream);

    // ---- CSR build: partition into region buckets -> per-region local build ----
    partition_kernel<<<(E + PCHUNK - 1) / PCHUNK, 256, 0, stream>>>(src, dst, rcnt, bucket, E, nreg, cap);
    csr_region_kernel<<<nreg, 256, 0, stream>>>(rcnt, bucket, offs, esrc, N, nreg, cap);

    // ---- weights prep + projection ----
    prep_w_kernel<<<(6 * H * H + 255) / 256, 256, 0, stream>>>(cw1, cw2, wt, 6 * H * H);
    proj_kernel<<<(N * 16 + 255) / 256, 256, 0, stream>>>(x, proj_w, proj_b, h, h8, N);

    int mlp_blocks = (N + 127) / 128;
    int gather_blocks = (N * 16 + 255) / 256;

    for (int l = 0; l < 3; ++l) {
        gather_agg_kernel<<<gather_blocks, 256, 0, stream>>>(offs, esrc, h8, buf, N);
        fused_mlp_kernel<<<mlp_blocks, 512, 0, stream>>>(
            h, buf, wt + (size_t)l * H * H, wt + (size_t)(3 + l) * H * H,
            cb1 + l * H, cb2 + l * H, h, h8, N);
    }

    pool_head_kernel<<<G, 128, 0, stream>>>(h, batch, sw, sb, ew, eb, dw, db, out, N, G);
}